// Round 6
// baseline (3023.484 us; speedup 1.0000x reference)
//
#include <hip/hip_runtime.h>
#include <math.h>

#define BATCH 16
#define NPTS  2048
#define DIM   768
#define KC    64
#define LP    136   // LDS row stride (floats); 136 % 32 == 8 -> 2 lanes/bank everywhere

typedef double d4 __attribute__((ext_vector_type(4)));
typedef unsigned long long ull;

// ---------------- normalize: fn = f / max(||f||,1e-12), fp64 norm ----------------
__global__ void normalize_k(const float* __restrict__ feat, float* __restrict__ fn, int cs) {
  const int rn = blockIdx.x;                 // ci*NPTS + n
  const int ci = rn >> 11, n = rn & (NPTS - 1);
  const float* src = feat + ((size_t)(cs + ci) * NPTS + n) * DIM;
  const int t = threadIdx.x;                 // 256 threads
  float f0 = src[t], f1 = src[t + 256], f2 = src[t + 512];
  double s = (double)f0 * (double)f0 + (double)f1 * (double)f1 + (double)f2 * (double)f2;
  for (int off = 32; off > 0; off >>= 1) s += __shfl_down(s, off);
  __shared__ double ps[4];
  __shared__ double rbc;
  const int lane = t & 63, wid = t >> 6;
  if (lane == 0) ps[wid] = s;
  __syncthreads();
  if (t == 0) {
    double tot = ps[0] + ps[1] + ps[2] + ps[3];
    rbc = fmax(sqrt(tot), 1e-12);
  }
  __syncthreads();
  const double r = rbc;
  float* dst = fn + ((size_t)ci * NPTS + n) * DIM;
  dst[t]       = (float)((double)f0 / r);
  dst[t + 256] = (float)((double)f1 / r);
  dst[t + 512] = (float)((double)f2 / r);
}

// ---------------- similarity: S = fn.fn^T (fp64 MFMA) + 0.5*exp(-d2/1e4) ----------------
// Upper-triangle 128x128 tiles (bx<=by); mirror_k fills the rest.
// KC=64 double-buffered fp32 LDS (139 KB dynamic): ONE barrier per chunk, loads for
// chunk c+1 issued at chunk top so 16K cycles of MFMA cover their latency. fp32->fp64
// cvt at fragment read is EXACT and k-accumulation order is unchanged -> S bit-identical
// to the verified round-2/4 kernels. LDS pointers via offset arithmetic (pointer-array
// initializers from addrspace(3) symbols don't compile on hipcc).
__global__ __launch_bounds__(256, 1) void gemm_k(const float* __restrict__ fn,
                                                 const float* __restrict__ coords,
                                                 float* __restrict__ S, int cs) {
  if (blockIdx.x > blockIdx.y) return;       // symmetry: skip strictly-lower tiles
  const int ci = blockIdx.z;
  const int i0 = blockIdx.x * 128;
  const int j0 = blockIdx.y * 128;
  const int tid  = threadIdx.x;              // 256
  const int lane = tid & 63, w = tid >> 6;
  const int wr = (w >> 1) * 64, wc = (w & 1) * 64;   // wave quadrant
  const int lo = lane & 15, quad = lane >> 4;

  extern __shared__ float lds[];             // [2][KC][LP] A then [2][KC][LP] B

  d4 acc[4][4];
#pragma unroll
  for (int tr = 0; tr < 4; ++tr)
#pragma unroll
    for (int tc = 0; tc < 4; ++tc) acc[tr][tc] = (d4){0.0, 0.0, 0.0, 0.0};

  const float* fb = fn + (size_t)ci * NPTS * DIM;
  const int row  = tid >> 1;       // staging row 0..127
  const int half = tid & 1;
  const int kk0  = half * 8;       // this thread's 8-k sub-band within each 16-k group
  const float* apBase = fb + (size_t)(i0 + row) * DIM + half * 8;
  const float* bpBase = fb + (size_t)(j0 + row) * DIM + half * 8;

  float4 la[8], lb[8];

  // ---- prologue: stage chunk 0 into buf 0 ----
#pragma unroll
  for (int g = 0; g < 4; ++g) {
    la[2 * g]     = *(const float4*)(apBase + g * 16);
    la[2 * g + 1] = *(const float4*)(apBase + g * 16 + 4);
    lb[2 * g]     = *(const float4*)(bpBase + g * 16);
    lb[2 * g + 1] = *(const float4*)(bpBase + g * 16 + 4);
  }
  {
    float* An = lds;                          // Abuf[0]
    float* Bn = lds + 2 * KC * LP;            // Bbuf[0]
#pragma unroll
    for (int g = 0; g < 4; ++g) {
      const int kb = g * 16 + kk0;
      float4 x0 = la[2 * g], x1 = la[2 * g + 1];
      An[(kb + 0) * LP + row] = x0.x; An[(kb + 1) * LP + row] = x0.y;
      An[(kb + 2) * LP + row] = x0.z; An[(kb + 3) * LP + row] = x0.w;
      An[(kb + 4) * LP + row] = x1.x; An[(kb + 5) * LP + row] = x1.y;
      An[(kb + 6) * LP + row] = x1.z; An[(kb + 7) * LP + row] = x1.w;
      float4 y0 = lb[2 * g], y1 = lb[2 * g + 1];
      Bn[(kb + 0) * LP + row] = y0.x; Bn[(kb + 1) * LP + row] = y0.y;
      Bn[(kb + 2) * LP + row] = y0.z; Bn[(kb + 3) * LP + row] = y0.w;
      Bn[(kb + 4) * LP + row] = y1.x; Bn[(kb + 5) * LP + row] = y1.y;
      Bn[(kb + 6) * LP + row] = y1.z; Bn[(kb + 7) * LP + row] = y1.w;
    }
  }
  __syncthreads();

  int p = 0;
#pragma unroll 1
  for (int c = 0; c < DIM / KC; ++c) {       // 12 chunks
    // issue next-chunk loads first: 16K cy of MFMA below covers their latency
    if (c + 1 < DIM / KC) {
      const int kc1 = (c + 1) * KC;
#pragma unroll
      for (int g = 0; g < 4; ++g) {
        la[2 * g]     = *(const float4*)(apBase + kc1 + g * 16);
        la[2 * g + 1] = *(const float4*)(apBase + kc1 + g * 16 + 4);
        lb[2 * g]     = *(const float4*)(bpBase + kc1 + g * 16);
        lb[2 * g + 1] = *(const float4*)(bpBase + kc1 + g * 16 + 4);
      }
    }
    const float* Ap = lds + p * KC * LP;
    const float* Bp = lds + 2 * KC * LP + p * KC * LP;
#pragma unroll
    for (int k4 = 0; k4 < KC; k4 += 4) {
      const int kk = k4 + quad;    // this lane's k index
      const float* Ar = Ap + kk * LP;
      const float* Br = Bp + kk * LP;
      double a0 = (double)Ar[wr + lo +  0];
      double a1 = (double)Ar[wr + lo + 16];
      double a2 = (double)Ar[wr + lo + 32];
      double a3 = (double)Ar[wr + lo + 48];
      double b0 = (double)Br[wc + lo +  0];
      double b1 = (double)Br[wc + lo + 16];
      double b2 = (double)Br[wc + lo + 32];
      double b3 = (double)Br[wc + lo + 48];
      acc[0][0] = __builtin_amdgcn_mfma_f64_16x16x4f64(a0, b0, acc[0][0], 0, 0, 0);
      acc[0][1] = __builtin_amdgcn_mfma_f64_16x16x4f64(a0, b1, acc[0][1], 0, 0, 0);
      acc[0][2] = __builtin_amdgcn_mfma_f64_16x16x4f64(a0, b2, acc[0][2], 0, 0, 0);
      acc[0][3] = __builtin_amdgcn_mfma_f64_16x16x4f64(a0, b3, acc[0][3], 0, 0, 0);
      acc[1][0] = __builtin_amdgcn_mfma_f64_16x16x4f64(a1, b0, acc[1][0], 0, 0, 0);
      acc[1][1] = __builtin_amdgcn_mfma_f64_16x16x4f64(a1, b1, acc[1][1], 0, 0, 0);
      acc[1][2] = __builtin_amdgcn_mfma_f64_16x16x4f64(a1, b2, acc[1][2], 0, 0, 0);
      acc[1][3] = __builtin_amdgcn_mfma_f64_16x16x4f64(a1, b3, acc[1][3], 0, 0, 0);
      acc[2][0] = __builtin_amdgcn_mfma_f64_16x16x4f64(a2, b0, acc[2][0], 0, 0, 0);
      acc[2][1] = __builtin_amdgcn_mfma_f64_16x16x4f64(a2, b1, acc[2][1], 0, 0, 0);
      acc[2][2] = __builtin_amdgcn_mfma_f64_16x16x4f64(a2, b2, acc[2][2], 0, 0, 0);
      acc[2][3] = __builtin_amdgcn_mfma_f64_16x16x4f64(a2, b3, acc[2][3], 0, 0, 0);
      acc[3][0] = __builtin_amdgcn_mfma_f64_16x16x4f64(a3, b0, acc[3][0], 0, 0, 0);
      acc[3][1] = __builtin_amdgcn_mfma_f64_16x16x4f64(a3, b1, acc[3][1], 0, 0, 0);
      acc[3][2] = __builtin_amdgcn_mfma_f64_16x16x4f64(a3, b2, acc[3][2], 0, 0, 0);
      acc[3][3] = __builtin_amdgcn_mfma_f64_16x16x4f64(a3, b3, acc[3][3], 0, 0, 0);
    }
    if (c + 1 < DIM / KC) {
      float* An = lds + (p ^ 1) * KC * LP;
      float* Bn = lds + 2 * KC * LP + (p ^ 1) * KC * LP;
#pragma unroll
      for (int g = 0; g < 4; ++g) {
        const int kb = g * 16 + kk0;
        float4 x0 = la[2 * g], x1 = la[2 * g + 1];
        An[(kb + 0) * LP + row] = x0.x; An[(kb + 1) * LP + row] = x0.y;
        An[(kb + 2) * LP + row] = x0.z; An[(kb + 3) * LP + row] = x0.w;
        An[(kb + 4) * LP + row] = x1.x; An[(kb + 5) * LP + row] = x1.y;
        An[(kb + 6) * LP + row] = x1.z; An[(kb + 7) * LP + row] = x1.w;
        float4 y0 = lb[2 * g], y1 = lb[2 * g + 1];
        Bn[(kb + 0) * LP + row] = y0.x; Bn[(kb + 1) * LP + row] = y0.y;
        Bn[(kb + 2) * LP + row] = y0.z; Bn[(kb + 3) * LP + row] = y0.w;
        Bn[(kb + 4) * LP + row] = y1.x; Bn[(kb + 5) * LP + row] = y1.y;
        Bn[(kb + 6) * LP + row] = y1.z; Bn[(kb + 7) * LP + row] = y1.w;
      }
      __syncthreads();
      p ^= 1;
    }
  }

  // ---- probe the true C/D slot->(row,col) mapping ----
  d4 p1 = (d4){0.0, 0.0, 0.0, 0.0}, p2 = (d4){0.0, 0.0, 0.0, 0.0};
  p1 = __builtin_amdgcn_mfma_f64_16x16x4f64((double)lane, 1.0, p1, 0, 0, 0);
  p2 = __builtin_amdgcn_mfma_f64_16x16x4f64(1.0, (double)lane, p2, 0, 0, 0);
  int rowp[4], colp[4];
#pragma unroll
  for (int r = 0; r < 4; ++r) {
    rowp[r] = ((int)((p1[r] - 96.0) * 0.25)) & 15;
    colp[r] = ((int)((p2[r] - 96.0) * 0.25)) & 15;
  }

  // epilogue: + 0.5 * exp(-sq_dist/10000), exp via 4th-order Taylor (x<=2e-4, err ~1e-20)
  const float* cb = coords + (size_t)(cs + ci) * NPTS * 2;
  float* Sb = S + (size_t)ci * NPTS * NPTS;
#pragma unroll
  for (int r = 0; r < 4; ++r) {
    const int rl = rowp[r], cl = colp[r];
#pragma unroll
    for (int tr = 0; tr < 4; ++tr) {
      const int rowi = i0 + wr + tr * 16 + rl;
      float2 pi = *(const float2*)(cb + 2 * rowi);
      const double cix = pi.x, ciy = pi.y;
#pragma unroll
      for (int tc = 0; tc < 4; ++tc) {
        const int colj = j0 + wc + tc * 16 + cl;
        float2 pj = *(const float2*)(cb + 2 * colj);
        double dx = cix - (double)pj.x, dy = ciy - (double)pj.y;
        double x = (dx * dx + dy * dy) * (1.0 / 10000.0);
        double e = 1.0 - x * (1.0 - x * (0.5 - x * ((1.0 / 6.0) - x * (1.0 / 24.0))));
        Sb[(size_t)rowi * NPTS + colj] = (float)(acc[tr][tc][r] + 0.5 * e);
      }
    }
  }
}

// ---------------- mirror: fill strictly-lower 128-blocks from upper triangle ----------------
__global__ __launch_bounds__(256) void mirror_k(float* __restrict__ S) {
  const int Cb = blockIdx.x, Rb = blockIdx.y;
  if ((Rb >> 1) <= (Cb >> 1)) return;
  float* Sb = S + (size_t)blockIdx.z * NPTS * NPTS;
  __shared__ float t[64][65];
  const int lane = threadIdx.x & 63, w = threadIdx.x >> 6;
#pragma unroll
  for (int p = 0; p < 16; ++p) {
    const int r = w + 4 * p;
    t[r][lane] = Sb[(size_t)(Cb * 64 + r) * NPTS + Rb * 64 + lane];
  }
  __syncthreads();
#pragma unroll
  for (int p = 0; p < 16; ++p) {
    const int r = w + 4 * p;
    Sb[(size_t)(Rb * 64 + r) * NPTS + Cb * 64 + lane] = t[lane][r];
  }
}

// ---------------- monotone fp32 key: a > b (float) <=> mono(a) > mono(b) (uint) ----------------
__device__ __forceinline__ unsigned mono(float f) {
  unsigned u = __float_as_uint(f);
  return (u & 0x80000000u) ? ~u : (u | 0x80000000u);
}

// ---------------- packed u64 wave argmax: max key, tie -> min index ----------------
// value packed as (key<<32) | (2047 - idx); 64-bit max over the wave via DPP on halves.
#define DPP64_STEP(X, CTRL, RMASK) do {                                                   \
  unsigned lo_ = (unsigned)(X), hi_ = (unsigned)((X) >> 32);                              \
  unsigned lo2_ = (unsigned)__builtin_amdgcn_update_dpp((int)lo_, (int)lo_, CTRL, RMASK, 0xf, false); \
  unsigned hi2_ = (unsigned)__builtin_amdgcn_update_dpp((int)hi_, (int)hi_, CTRL, RMASK, 0xf, false); \
  ull o_ = ((ull)hi2_ << 32) | lo2_;                                                      \
  if (o_ > (X)) (X) = o_;                                                                 \
} while (0)

__device__ __forceinline__ ull wave_amax64(ull x) {
  DPP64_STEP(x, 0x111, 0xf);   // row_shr:1
  DPP64_STEP(x, 0x112, 0xf);   // row_shr:2
  DPP64_STEP(x, 0x114, 0xf);   // row_shr:4
  DPP64_STEP(x, 0x118, 0xf);   // row_shr:8
  DPP64_STEP(x, 0x142, 0xa);   // row_bcast:15 -> rows 1,3
  DPP64_STEP(x, 0x143, 0xc);   // row_bcast:31 -> rows 2,3
  unsigned lo = (unsigned)__builtin_amdgcn_readlane((int)(unsigned)x, 63);
  unsigned hi = (unsigned)__builtin_amdgcn_readlane((int)(unsigned)(x >> 32), 63);
  return ((ull)hi << 32) | lo;
}

// ---------------- cand_k: exact top-7 + tau(=8th max) per row (diag excluded) + fp64 rowsum ----
// Output: cand8[row*8 + e] for e<7: (mono(val)<<32)|(2047-idx). Slot 7: (mono(8th max)<<32).
__global__ __launch_bounds__(64) void cand_k(const float* __restrict__ S,
                                             ull* __restrict__ cand8,
                                             double* __restrict__ rs) {
  const size_t r = blockIdx.x;               // ci*NPTS + row
  const int row = (int)(r & (NPTS - 1));
  const float* rowp = S + r * NPTS;
  const int lane = threadIdx.x;

  float4 q[8];
  double sum = 0.0;
#pragma unroll
  for (int c = 0; c < 8; ++c) {
    q[c] = ((const float4*)rowp)[c * 64 + lane];
    sum += (double)q[c].x; sum += (double)q[c].y; sum += (double)q[c].z; sum += (double)q[c].w;
  }
  {
    double s2 = sum;
    for (int off = 32; off > 0; off >>= 1) s2 += __shfl_down(s2, off);
    if (lane == 0) rs[r] = s2;
  }

  // removal mask over this lane's 32 positions (bit 4c+s); pre-remove the diagonal.
  unsigned rem = 0;
  const int dd = row - 4 * lane;             // == c*256 + s if this lane owns the diag
  if (dd >= 0 && dd < 2048 && (dd & 0xFC) == 0) rem = 1u << (((dd >> 8) << 2) | (dd & 3));

  float bv; int bp;
  auto rescan = [&]() {
    bv = -INFINITY; bp = 0;
#pragma unroll
    for (int c = 0; c < 8; ++c) {
      const float xs0 = q[c].x, xs1 = q[c].y, xs2 = q[c].z, xs3 = q[c].w;
      float x0 = ((rem >> (4 * c + 0)) & 1u) ? -INFINITY : xs0;
      float x1 = ((rem >> (4 * c + 1)) & 1u) ? -INFINITY : xs1;
      float x2 = ((rem >> (4 * c + 2)) & 1u) ? -INFINITY : xs2;
      float x3 = ((rem >> (4 * c + 3)) & 1u) ? -INFINITY : xs3;
      if (x0 > bv) { bv = x0; bp = 4 * c + 0; }
      if (x1 > bv) { bv = x1; bp = 4 * c + 1; }
      if (x2 > bv) { bv = x2; bp = 4 * c + 2; }
      if (x3 > bv) { bv = x3; bp = 4 * c + 3; }
    }
  };
  rescan();

#pragma unroll 1
  for (int rnd = 0; rnd < 8; ++rnd) {
    const int gi = ((bp >> 2) << 8) + 4 * lane + (bp & 3);   // global column index
    const ull pk = ((ull)mono(bv) << 32) | (unsigned)(2047 - gi);
    const ull red = wave_amax64(pk);
    if (rnd < 7) {
      if (lane == 0) cand8[r * 8 + rnd] = red;
      if (pk == red) { rem |= 1u << bp; rescan(); }          // winner lane removes + rescans
    } else {
      if (lane == 0) cand8[r * 8 + 7] = (red >> 32) << 32;   // tau = 8th max, idx field 0
    }
  }
}

// ---------------- greedy traversal: LDS-resident compact candidate table ----------------
__global__ __launch_bounds__(64) void traverse_k(const float* __restrict__ S,
                                                 const ull* __restrict__ cand8,
                                                 const double* __restrict__ rs,
                                                 float* __restrict__ order_f, int cs) {
  extern __shared__ ull tabL[];              // [NPTS*8]
  const int ci = blockIdx.x;
  const int gb = cs + ci;
  const int lane = threadIdx.x;

  // stage candidate table: 128KB, 8 loads in flight per burst
  {
    float4* ls = (float4*)tabL;
    const float4* gs = (const float4*)(cand8 + (size_t)ci * NPTS * 8);
#pragma unroll 1
    for (int i0 = 0; i0 < 8192; i0 += 512) {
      float4 t[8];
#pragma unroll
      for (int j = 0; j < 8; ++j) t[j] = gs[i0 + j * 64 + lane];
#pragma unroll
      for (int j = 0; j < 8; ++j) ls[i0 + j * 64 + lane] = t[j];
    }
  }
  __syncthreads();

  // start node: argmax of fp64 rowsum (tie -> min index)
  const double* rb = rs + (size_t)ci * NPTS;
  double dv = -1.0e300; int di = 0;
#pragma unroll
  for (int c = 0; c < 32; ++c) {
    int j = c * 64 + lane;
    double v = rb[j];
    if (v > dv) { dv = v; di = j; }
  }
  for (int off = 32; off > 0; off >>= 1) {
    double vo = __shfl_down(dv, off);
    int io = __shfl_down(di, off);
    if (vo > dv || (vo == dv && io < di)) { dv = vo; di = io; }
  }
  int cur = __shfl(di, 0);

  unsigned vis = 0, visw = 0;
  if (lane == ((cur >> 2) & 63)) vis |= 1u << (((cur >> 8) << 2) | (cur & 3));
  if (lane == (cur >> 5))        visw |= 1u << (cur & 31);
  if (lane == 0) order_f[(size_t)gb * NPTS] = (float)cur;

  const float* Sb = S + (size_t)ci * NPTS * NPTS;

  auto step = [&](int s, float4 (&v)[8]) {
    // speculative prefetch of row cur (consumed only on slow path)
    const float4* rowp = (const float4*)(Sb + (size_t)cur * NPTS);
#pragma unroll
    for (int c = 0; c < 8; ++c) v[c] = rowp[c * 64 + lane];
    __builtin_amdgcn_sched_barrier(0);       // pin issue point: loads first, then LDS path

    const ull e = tabL[cur * 8 + (lane & 7)];                 // broadcast ds_read_b64
    const unsigned tauv = (unsigned)__shfl((int)(unsigned)(e >> 32), 7);
    const unsigned idx = 2047u - (unsigned)(e & 0xFFFFFFFFu);
    const unsigned wv = (unsigned)__shfl((int)visw, (int)(idx >> 5));
    const ull masked = (((lane & 7) == 7) || ((wv >> (idx & 31)) & 1u)) ? 0ull : e;
    const ull m = wave_amax64(masked);
    int nxt;
    if ((unsigned)(m >> 32) > tauv) {
      nxt = (int)(2047u - (unsigned)(m & 0xFFFFFFFFu));
    } else {
      // slow path: full masked row scan (v[] already in flight)
      float bvv = -INFINITY; int bi = 0;
#pragma unroll
      for (int c = 0; c < 8; ++c) {
        const int base = c * 256 + 4 * lane;
        float x0 = (vis & (1u << (4 * c + 0))) ? -INFINITY : v[c].x;
        float x1 = (vis & (1u << (4 * c + 1))) ? -INFINITY : v[c].y;
        float x2 = (vis & (1u << (4 * c + 2))) ? -INFINITY : v[c].z;
        float x3 = (vis & (1u << (4 * c + 3))) ? -INFINITY : v[c].w;
        if (x0 > bvv) { bvv = x0; bi = base + 0; }
        if (x1 > bvv) { bvv = x1; bi = base + 1; }
        if (x2 > bvv) { bvv = x2; bi = base + 2; }
        if (x3 > bvv) { bvv = x3; bi = base + 3; }
      }
      const ull pk = ((ull)mono(bvv) << 32) | (unsigned)(2047 - bi);
      const ull mm = wave_amax64(pk);
      nxt = (int)(2047u - (unsigned)(mm & 0xFFFFFFFFu));
    }
    if (lane == ((nxt >> 2) & 63)) vis |= 1u << (((nxt >> 8) << 2) | (nxt & 3));
    if (lane == (nxt >> 5))        visw |= 1u << (nxt & 31);
    if (lane == 0) order_f[(size_t)gb * NPTS + s] = (float)nxt;
    cur = nxt;
  };

  float4 va[8], vb[8];
  int s = 1;
  for (; s + 1 < NPTS; s += 2) {             // 1023 pairs
    step(s, va);
    step(s + 1, vb);
  }
  step(s, va);                               // final odd step (s = 2047)
}

// ---------------- gather: reordered = features[order] ----------------
__global__ void gather_k(const float* __restrict__ feat, const float* __restrict__ order_f,
                         float* __restrict__ out) {
  const int bk = blockIdx.x;
  const int b = bk >> 11, k = bk & (NPTS - 1);
  const int idx = (int)order_f[(size_t)b * NPTS + k];
  const float4* src = (const float4*)(feat + ((size_t)b * NPTS + idx) * DIM);
  float4* dst = (float4*)(out + ((size_t)b * NPTS + k) * DIM);
  dst[threadIdx.x] = src[threadIdx.x];
}

extern "C" void kernel_launch(void* const* d_in, const int* in_sizes, int n_in,
                              void* d_out, int out_size, void* d_ws, size_t ws_size,
                              hipStream_t stream) {
  const float* features = (const float*)d_in[0];
  const float* coords   = (const float*)d_in[1];
  float* out = (float*)d_out;
  float* order_f = out + (size_t)BATCH * NPTS * DIM;

  const int gemm_lds = 4 * KC * LP * 4;      // 139264 B: 2 bufs x (A+B) x [KC][LP] fp32

  // one-time: allow >64 KiB dynamic LDS (host-side non-stream calls, graph-capture safe)
  static bool attr_done = false;
  if (!attr_done) {
    (void)hipFuncSetAttribute((const void*)traverse_k,
                              hipFuncAttributeMaxDynamicSharedMemorySize, 131072);
    (void)hipFuncSetAttribute((const void*)gemm_k,
                              hipFuncAttributeMaxDynamicSharedMemorySize, gemm_lds);
    attr_done = true;
  }

  // ws per batch: rs (N*8) + S (N*N*4) + fn (N*D*4) + cand8 (N*8*8)
  const size_t per_b = (size_t)NPTS * 8 + (size_t)NPTS * NPTS * 4 +
                       (size_t)NPTS * DIM * 4 + (size_t)NPTS * 8 * 8;
  int C = BATCH;
  while (C > 1 && per_b * (size_t)C > ws_size) C >>= 1;

  char* wp = (char*)d_ws;
  double* rowsum = (double*)wp;               wp += (size_t)C * NPTS * 8;
  float*  S      = (float*)wp;                wp += (size_t)C * NPTS * NPTS * 4;
  float*  fn     = (float*)wp;                wp += (size_t)C * NPTS * DIM * 4;
  ull*    cand8  = (ull*)wp;

  for (int cs = 0; cs < BATCH; cs += C) {
    normalize_k<<<dim3(C * NPTS), dim3(256), 0, stream>>>(features, fn, cs);
    gemm_k<<<dim3(16, 16, C), dim3(256), gemm_lds, stream>>>(fn, coords, S, cs);
    mirror_k<<<dim3(32, 32, C), dim3(256), 0, stream>>>(S);
    cand_k<<<dim3(C * NPTS), dim3(64), 0, stream>>>(S, cand8, rowsum);
    traverse_k<<<dim3(C), dim3(64), 131072, stream>>>(S, cand8, rowsum, order_f, cs);
  }
  gather_k<<<dim3(BATCH * NPTS), dim3(192), 0, stream>>>(features, order_f, out);
}

// Round 8
// 2598.220 us; speedup vs baseline: 1.1637x; 1.1637x over previous
//
#include <hip/hip_runtime.h>
#include <math.h>

#define BATCH 16
#define NPTS  2048
#define DIM   768
#define NCH   24      // 768 / 32 k-chunks
#define PAD   40      // LDS row stride in bf16 (80B): b128 reads 2-way (free)

typedef double d4 __attribute__((ext_vector_type(4)));
typedef unsigned long long ull;
typedef float f32x4 __attribute__((ext_vector_type(4)));
typedef short bf8 __attribute__((ext_vector_type(8)));          // 8 bf16 = 4 VGPR
typedef unsigned short u16x8 __attribute__((ext_vector_type(8)));

#define PL ((size_t)NPTS * DIM)   // plane stride (elements)

// RNE fp32 -> bf16 (finite inputs)
__device__ __forceinline__ unsigned short f2bf(float x) {
  unsigned u = __float_as_uint(x);
  u += 0x7FFFu + ((u >> 16) & 1u);
  return (unsigned short)(u >> 16);
}
__device__ __forceinline__ float bf2f(unsigned short b) {
  return __uint_as_float(((unsigned)b) << 16);
}

// ---------------- normalize + split-3: fn = f/max(||f||,1e-12) -> 3 bf16 planes ----------------
// b1=bf16(w), b2=bf16(w-b1), b3=bf16(w-b1-b2); residuals exact (Sterbenz) so
// w = b1+b2+b3 + eps, |eps| <= 2^-27|w|.
__global__ void normalize_k(const float* __restrict__ feat, unsigned short* __restrict__ sp, int cs) {
  const int rn = blockIdx.x;                 // ci*NPTS + n
  const int ci = rn >> 11, n = rn & (NPTS - 1);
  const float* src = feat + ((size_t)(cs + ci) * NPTS + n) * DIM;
  const int t = threadIdx.x;                 // 256 threads
  float f0 = src[t], f1 = src[t + 256], f2 = src[t + 512];
  double s = (double)f0 * (double)f0 + (double)f1 * (double)f1 + (double)f2 * (double)f2;
  for (int off = 32; off > 0; off >>= 1) s += __shfl_down(s, off);
  __shared__ double ps[4];
  __shared__ double rbc;
  const int lane = t & 63, wid = t >> 6;
  if (lane == 0) ps[wid] = s;
  __syncthreads();
  if (t == 0) {
    double tot = ps[0] + ps[1] + ps[2] + ps[3];
    rbc = fmax(sqrt(tot), 1e-12);
  }
  __syncthreads();
  const double r = rbc;
  unsigned short* base = sp + (size_t)ci * 3 * PL + (size_t)n * DIM;
  float fv[3] = { f0, f1, f2 };
#pragma unroll
  for (int e = 0; e < 3; ++e) {
    const int d = t + e * 256;
    float wv = (float)((double)fv[e] / r);
    unsigned short b1 = f2bf(wv); float r1 = wv - bf2f(b1);
    unsigned short b2 = f2bf(r1); float r2 = r1 - bf2f(b2);
    unsigned short b3 = f2bf(r2);
    base[d] = b1; base[PL + d] = b2; base[2 * PL + d] = b3;
  }
}

// ---------------- similarity: S = fn.fn^T via split-3 bf16 MFMA + 0.5*exp(-d2/1e4) ------------
// Upper-triangle 128x128 tiles (bx<=by); mirror_k fills the rest.
// Per 16x16 output tile per k32: 6 bf16 MFMAs into 3 fp32 accumulators
// (hi=a1b1, mid=a1b2+a2b1, lo=a1b3+a2b2+a3b1); dropped terms < 2^-27.
// Final S = (double)hi+mid+lo + spatial. Total error ~1e-7 (< reference's own
// fp32 noise ~1.6e-6, which the greedy decisions provably tolerate: absmax==0
// held with fp64 S vs the fp32 reference).
// k-slot safety: A and B fragments use the SAME lane->(idx,k-slot) map, so the
// contraction is invariant to the HW's true slot->k bijection; C/D is probed.
__global__ __launch_bounds__(256, 1) void gemm_k(const unsigned short* __restrict__ sp,
                                                 const float* __restrict__ coords,
                                                 float* __restrict__ S, int cs) {
  if (blockIdx.x > blockIdx.y) return;       // symmetry: skip strictly-lower tiles
  const int ci = blockIdx.z;
  const int i0 = blockIdx.x * 128;
  const int j0 = blockIdx.y * 128;
  const int tid  = threadIdx.x;              // 256
  const int lane = tid & 63, w = tid >> 6;
  const int wr = (w >> 1) * 64, wc = (w & 1) * 64;   // wave quadrant
  const int lo = lane & 15, quad = lane >> 4;

  __shared__ unsigned short At[3][128][PAD]; // 30720 B
  __shared__ unsigned short Bt[3][128][PAD]; // 30720 B

  f32x4 aH[4][4], aM[4][4], aL[4][4];
#pragma unroll
  for (int tr = 0; tr < 4; ++tr)
#pragma unroll
    for (int tc = 0; tc < 4; ++tc) {
      aH[tr][tc] = (f32x4){0.f, 0.f, 0.f, 0.f};
      aM[tr][tc] = (f32x4){0.f, 0.f, 0.f, 0.f};
      aL[tr][tc] = (f32x4){0.f, 0.f, 0.f, 0.f};
    }

  const unsigned short* pb = sp + (size_t)ci * 3 * PL;
  const int row  = tid >> 1;       // staging row 0..127
  const int half = tid & 1;        // 16-k sub-band
  const unsigned short* ag = pb + (size_t)(i0 + row) * DIM + half * 16;
  const unsigned short* bg = pb + (size_t)(j0 + row) * DIM + half * 16;

  u16x8 ra[3][2], rb[3][2];
  // prefetch chunk 0
#pragma unroll
  for (int p = 0; p < 3; ++p) {
    ra[p][0] = *(const u16x8*)(ag + (size_t)p * PL);
    ra[p][1] = *(const u16x8*)(ag + (size_t)p * PL + 8);
    rb[p][0] = *(const u16x8*)(bg + (size_t)p * PL);
    rb[p][1] = *(const u16x8*)(bg + (size_t)p * PL + 8);
  }

#pragma unroll 1
  for (int c = 0; c < NCH; ++c) {
    __syncthreads();               // previous chunk's readers done
#pragma unroll
    for (int p = 0; p < 3; ++p) {
      *(u16x8*)&At[p][row][half * 16]     = ra[p][0];
      *(u16x8*)&At[p][row][half * 16 + 8] = ra[p][1];
      *(u16x8*)&Bt[p][row][half * 16]     = rb[p][0];
      *(u16x8*)&Bt[p][row][half * 16 + 8] = rb[p][1];
    }
    __syncthreads();
    if (c + 1 < NCH) {             // prefetch next chunk; overlaps MFMA below
      const int kc = (c + 1) * 32;
#pragma unroll
      for (int p = 0; p < 3; ++p) {
        ra[p][0] = *(const u16x8*)(ag + (size_t)p * PL + kc);
        ra[p][1] = *(const u16x8*)(ag + (size_t)p * PL + kc + 8);
        rb[p][0] = *(const u16x8*)(bg + (size_t)p * PL + kc);
        rb[p][1] = *(const u16x8*)(bg + (size_t)p * PL + kc + 8);
      }
    }
    bf8 A0[4], A1[4], A2[4], B0[4], B1[4], B2[4];
#pragma unroll
    for (int t = 0; t < 4; ++t) {
      const int rA = wr + t * 16 + lo, rB = wc + t * 16 + lo, k8 = quad * 8;
      A0[t] = *(const bf8*)&At[0][rA][k8];
      A1[t] = *(const bf8*)&At[1][rA][k8];
      A2[t] = *(const bf8*)&At[2][rA][k8];
      B0[t] = *(const bf8*)&Bt[0][rB][k8];
      B1[t] = *(const bf8*)&Bt[1][rB][k8];
      B2[t] = *(const bf8*)&Bt[2][rB][k8];
    }
#pragma unroll
    for (int tr = 0; tr < 4; ++tr)
#pragma unroll
      for (int tc = 0; tc < 4; ++tc) {
        aH[tr][tc] = __builtin_amdgcn_mfma_f32_16x16x32_bf16(A0[tr], B0[tc], aH[tr][tc], 0, 0, 0);
        aM[tr][tc] = __builtin_amdgcn_mfma_f32_16x16x32_bf16(A0[tr], B1[tc], aM[tr][tc], 0, 0, 0);
        aM[tr][tc] = __builtin_amdgcn_mfma_f32_16x16x32_bf16(A1[tr], B0[tc], aM[tr][tc], 0, 0, 0);
        aL[tr][tc] = __builtin_amdgcn_mfma_f32_16x16x32_bf16(A0[tr], B2[tc], aL[tr][tc], 0, 0, 0);
        aL[tr][tc] = __builtin_amdgcn_mfma_f32_16x16x32_bf16(A1[tr], B1[tc], aL[tr][tc], 0, 0, 0);
        aL[tr][tc] = __builtin_amdgcn_mfma_f32_16x16x32_bf16(A2[tr], B0[tc], aL[tr][tc], 0, 0, 0);
      }
  }

  // ---- probe the true C/D slot->(row,col) mapping (exact small ints in bf16/fp32) ----
  {
    const unsigned short encv = f2bf((float)lo);
    const unsigned short onev = f2bf(1.0f);
    bf8 enc, one;
#pragma unroll
    for (int t = 0; t < 8; ++t) { enc[t] = (short)encv; one[t] = (short)onev; }
    f32x4 z = (f32x4){0.f, 0.f, 0.f, 0.f};
    f32x4 d1 = __builtin_amdgcn_mfma_f32_16x16x32_bf16(enc, one, z, 0, 0, 0); // = 32*row
    f32x4 d2 = __builtin_amdgcn_mfma_f32_16x16x32_bf16(one, enc, z, 0, 0, 0); // = 32*col
    int rowp[4], colp[4];
#pragma unroll
    for (int r = 0; r < 4; ++r) {
      rowp[r] = ((int)(d1[r] * (1.0f / 32.0f))) & 15;
      colp[r] = ((int)(d2[r] * (1.0f / 32.0f))) & 15;
    }

    // epilogue: S = hi+mid+lo (fp64 sum) + 0.5*exp(-d2/1e4) (4th-order Taylor, exact regime)
    const float* cb = coords + (size_t)(cs + ci) * NPTS * 2;
    float* Sb = S + (size_t)ci * NPTS * NPTS;
#pragma unroll
    for (int r = 0; r < 4; ++r) {
      const int rl = rowp[r], cl = colp[r];
#pragma unroll
      for (int tr = 0; tr < 4; ++tr) {
        const int rowi = i0 + wr + tr * 16 + rl;
        float2 pi = *(const float2*)(cb + 2 * rowi);
        const double cix = pi.x, ciy = pi.y;
#pragma unroll
        for (int tc = 0; tc < 4; ++tc) {
          const int colj = j0 + wc + tc * 16 + cl;
          float2 pj = *(const float2*)(cb + 2 * colj);
          double dx = cix - (double)pj.x, dy = ciy - (double)pj.y;
          double x = (dx * dx + dy * dy) * (1.0 / 10000.0);
          double e = 1.0 - x * (1.0 - x * (0.5 - x * ((1.0 / 6.0) - x * (1.0 / 24.0))));
          double sem = (double)aH[tr][tc][r] + (double)aM[tr][tc][r] + (double)aL[tr][tc][r];
          Sb[(size_t)rowi * NPTS + colj] = (float)(sem + 0.5 * e);
        }
      }
    }
  }
}

// ---------------- mirror: fill strictly-lower 128-blocks from upper triangle ----------------
__global__ __launch_bounds__(256) void mirror_k(float* __restrict__ S) {
  const int Cb = blockIdx.x, Rb = blockIdx.y;
  if ((Rb >> 1) <= (Cb >> 1)) return;
  float* Sb = S + (size_t)blockIdx.z * NPTS * NPTS;
  __shared__ float t[64][65];
  const int lane = threadIdx.x & 63, w = threadIdx.x >> 6;
#pragma unroll
  for (int p = 0; p < 16; ++p) {
    const int r = w + 4 * p;
    t[r][lane] = Sb[(size_t)(Cb * 64 + r) * NPTS + Rb * 64 + lane];
  }
  __syncthreads();
#pragma unroll
  for (int p = 0; p < 16; ++p) {
    const int r = w + 4 * p;
    Sb[(size_t)(Rb * 64 + r) * NPTS + Cb * 64 + lane] = t[lane][r];
  }
}

// ---------------- monotone fp32 key ----------------
__device__ __forceinline__ unsigned mono(float f) {
  unsigned u = __float_as_uint(f);
  return (u & 0x80000000u) ? ~u : (u | 0x80000000u);
}

// ---------------- packed u64 wave argmax: max key, tie -> min index ----------------
#define DPP64_STEP(X, CTRL, RMASK) do {                                                   \
  unsigned lo_ = (unsigned)(X), hi_ = (unsigned)((X) >> 32);                              \
  unsigned lo2_ = (unsigned)__builtin_amdgcn_update_dpp((int)lo_, (int)lo_, CTRL, RMASK, 0xf, false); \
  unsigned hi2_ = (unsigned)__builtin_amdgcn_update_dpp((int)hi_, (int)hi_, CTRL, RMASK, 0xf, false); \
  ull o_ = ((ull)hi2_ << 32) | lo2_;                                                      \
  if (o_ > (X)) (X) = o_;                                                                 \
} while (0)

__device__ __forceinline__ ull wave_amax64(ull x) {
  DPP64_STEP(x, 0x111, 0xf);
  DPP64_STEP(x, 0x112, 0xf);
  DPP64_STEP(x, 0x114, 0xf);
  DPP64_STEP(x, 0x118, 0xf);
  DPP64_STEP(x, 0x142, 0xa);
  DPP64_STEP(x, 0x143, 0xc);
  unsigned lo = (unsigned)__builtin_amdgcn_readlane((int)(unsigned)x, 63);
  unsigned hi = (unsigned)__builtin_amdgcn_readlane((int)(unsigned)(x >> 32), 63);
  return ((ull)hi << 32) | lo;
}

// ---------------- cand_k: exact top-7 + tau(=8th max) per row + fp64 rowsum ----------------
__global__ __launch_bounds__(64) void cand_k(const float* __restrict__ S,
                                             ull* __restrict__ cand8,
                                             double* __restrict__ rs) {
  const size_t r = blockIdx.x;               // ci*NPTS + row
  const int row = (int)(r & (NPTS - 1));
  const float* rowp = S + r * NPTS;
  const int lane = threadIdx.x;

  float4 q[8];
  double sum = 0.0;
#pragma unroll
  for (int c = 0; c < 8; ++c) {
    q[c] = ((const float4*)rowp)[c * 64 + lane];
    sum += (double)q[c].x; sum += (double)q[c].y; sum += (double)q[c].z; sum += (double)q[c].w;
  }
  {
    double s2 = sum;
    for (int off = 32; off > 0; off >>= 1) s2 += __shfl_down(s2, off);
    if (lane == 0) rs[r] = s2;
  }

  unsigned rem = 0;
  const int dd = row - 4 * lane;
  if (dd >= 0 && dd < 2048 && (dd & 0xFC) == 0) rem = 1u << (((dd >> 8) << 2) | (dd & 3));

  float bv; int bp;
  auto rescan = [&]() {
    bv = -INFINITY; bp = 0;
#pragma unroll
    for (int c = 0; c < 8; ++c) {
      const float xs0 = q[c].x, xs1 = q[c].y, xs2 = q[c].z, xs3 = q[c].w;
      float x0 = ((rem >> (4 * c + 0)) & 1u) ? -INFINITY : xs0;
      float x1 = ((rem >> (4 * c + 1)) & 1u) ? -INFINITY : xs1;
      float x2 = ((rem >> (4 * c + 2)) & 1u) ? -INFINITY : xs2;
      float x3 = ((rem >> (4 * c + 3)) & 1u) ? -INFINITY : xs3;
      if (x0 > bv) { bv = x0; bp = 4 * c + 0; }
      if (x1 > bv) { bv = x1; bp = 4 * c + 1; }
      if (x2 > bv) { bv = x2; bp = 4 * c + 2; }
      if (x3 > bv) { bv = x3; bp = 4 * c + 3; }
    }
  };
  rescan();

#pragma unroll 1
  for (int rnd = 0; rnd < 8; ++rnd) {
    const int gi = ((bp >> 2) << 8) + 4 * lane + (bp & 3);
    const ull pk = ((ull)mono(bv) << 32) | (unsigned)(2047 - gi);
    const ull red = wave_amax64(pk);
    if (rnd < 7) {
      if (lane == 0) cand8[r * 8 + rnd] = red;
      if (pk == red) { rem |= 1u << bp; rescan(); }
    } else {
      if (lane == 0) cand8[r * 8 + 7] = (red >> 32) << 32;
    }
  }
}

// ---------------- greedy traversal: LDS-resident compact candidate table ----------------
__global__ __launch_bounds__(64) void traverse_k(const float* __restrict__ S,
                                                 const ull* __restrict__ cand8,
                                                 const double* __restrict__ rs,
                                                 float* __restrict__ order_f, int cs) {
  extern __shared__ ull tabL[];              // [NPTS*8]
  const int ci = blockIdx.x;
  const int gb = cs + ci;
  const int lane = threadIdx.x;

  {
    float4* ls = (float4*)tabL;
    const float4* gs = (const float4*)(cand8 + (size_t)ci * NPTS * 8);
#pragma unroll 1
    for (int i0 = 0; i0 < 8192; i0 += 512) {
      float4 t[8];
#pragma unroll
      for (int j = 0; j < 8; ++j) t[j] = gs[i0 + j * 64 + lane];
#pragma unroll
      for (int j = 0; j < 8; ++j) ls[i0 + j * 64 + lane] = t[j];
    }
  }
  __syncthreads();

  const double* rb = rs + (size_t)ci * NPTS;
  double dv = -1.0e300; int di = 0;
#pragma unroll
  for (int c = 0; c < 32; ++c) {
    int j = c * 64 + lane;
    double v = rb[j];
    if (v > dv) { dv = v; di = j; }
  }
  for (int off = 32; off > 0; off >>= 1) {
    double vo = __shfl_down(dv, off);
    int io = __shfl_down(di, off);
    if (vo > dv || (vo == dv && io < di)) { dv = vo; di = io; }
  }
  int cur = __shfl(di, 0);

  unsigned vis = 0, visw = 0;
  if (lane == ((cur >> 2) & 63)) vis |= 1u << (((cur >> 8) << 2) | (cur & 3));
  if (lane == (cur >> 5))        visw |= 1u << (cur & 31);
  if (lane == 0) order_f[(size_t)gb * NPTS] = (float)cur;

  const float* Sb = S + (size_t)ci * NPTS * NPTS;

  auto step = [&](int s, float4 (&v)[8]) {
    const float4* rowp = (const float4*)(Sb + (size_t)cur * NPTS);
#pragma unroll
    for (int c = 0; c < 8; ++c) v[c] = rowp[c * 64 + lane];
    __builtin_amdgcn_sched_barrier(0);

    const ull e = tabL[cur * 8 + (lane & 7)];
    const unsigned tauv = (unsigned)__shfl((int)(unsigned)(e >> 32), 7);
    const unsigned idx = 2047u - (unsigned)(e & 0xFFFFFFFFu);
    const unsigned wv = (unsigned)__shfl((int)visw, (int)(idx >> 5));
    const ull masked = (((lane & 7) == 7) || ((wv >> (idx & 31)) & 1u)) ? 0ull : e;
    const ull m = wave_amax64(masked);
    int nxt;
    if ((unsigned)(m >> 32) > tauv) {
      nxt = (int)(2047u - (unsigned)(m & 0xFFFFFFFFu));
    } else {
      float bvv = -INFINITY; int bi = 0;
#pragma unroll
      for (int c = 0; c < 8; ++c) {
        const int base = c * 256 + 4 * lane;
        float x0 = (vis & (1u << (4 * c + 0))) ? -INFINITY : v[c].x;
        float x1 = (vis & (1u << (4 * c + 1))) ? -INFINITY : v[c].y;
        float x2 = (vis & (1u << (4 * c + 2))) ? -INFINITY : v[c].z;
        float x3 = (vis & (1u << (4 * c + 3))) ? -INFINITY : v[c].w;
        if (x0 > bvv) { bvv = x0; bi = base + 0; }
        if (x1 > bvv) { bvv = x1; bi = base + 1; }
        if (x2 > bvv) { bvv = x2; bi = base + 2; }
        if (x3 > bvv) { bvv = x3; bi = base + 3; }
      }
      const ull pk = ((ull)mono(bvv) << 32) | (unsigned)(2047 - bi);
      const ull mm = wave_amax64(pk);
      nxt = (int)(2047u - (unsigned)(mm & 0xFFFFFFFFu));
    }
    if (lane == ((nxt >> 2) & 63)) vis |= 1u << (((nxt >> 8) << 2) | (nxt & 3));
    if (lane == (nxt >> 5))        visw |= 1u << (nxt & 31);
    if (lane == 0) order_f[(size_t)gb * NPTS + s] = (float)nxt;
    cur = nxt;
  };

  float4 va[8], vb[8];
  int s = 1;
  for (; s + 1 < NPTS; s += 2) {
    step(s, va);
    step(s + 1, vb);
  }
  step(s, va);
}

// ---------------- gather: reordered = features[order] ----------------
__global__ void gather_k(const float* __restrict__ feat, const float* __restrict__ order_f,
                         float* __restrict__ out) {
  const int bk = blockIdx.x;
  const int b = bk >> 11, k = bk & (NPTS - 1);
  const int idx = (int)order_f[(size_t)b * NPTS + k];
  const float4* src = (const float4*)(feat + ((size_t)b * NPTS + idx) * DIM);
  float4* dst = (float4*)(out + ((size_t)b * NPTS + k) * DIM);
  dst[threadIdx.x] = src[threadIdx.x];
}

extern "C" void kernel_launch(void* const* d_in, const int* in_sizes, int n_in,
                              void* d_out, int out_size, void* d_ws, size_t ws_size,
                              hipStream_t stream) {
  const float* features = (const float*)d_in[0];
  const float* coords   = (const float*)d_in[1];
  float* out = (float*)d_out;
  float* order_f = out + (size_t)BATCH * NPTS * DIM;

  static bool attr_done = false;
  if (!attr_done) {
    (void)hipFuncSetAttribute((const void*)traverse_k,
                              hipFuncAttributeMaxDynamicSharedMemorySize, 131072);
    attr_done = true;
  }

  // ws per batch: rs (N*8) + S (N*N*4) + splits (3*N*D*2) + cand8 (N*8*8)
  const size_t per_b = (size_t)NPTS * 8 + (size_t)NPTS * NPTS * 4 +
                       (size_t)3 * NPTS * DIM * 2 + (size_t)NPTS * 8 * 8;
  int C = BATCH;
  while (C > 1 && per_b * (size_t)C > ws_size) C >>= 1;

  char* wp = (char*)d_ws;
  double*         rowsum = (double*)wp;         wp += (size_t)C * NPTS * 8;
  float*          S      = (float*)wp;          wp += (size_t)C * NPTS * NPTS * 4;
  unsigned short* splits = (unsigned short*)wp; wp += (size_t)C * 3 * NPTS * DIM * 2;
  ull*            cand8  = (ull*)wp;

  for (int cs = 0; cs < BATCH; cs += C) {
    normalize_k<<<dim3(C * NPTS), dim3(256), 0, stream>>>(features, splits, cs);
    gemm_k<<<dim3(16, 16, C), dim3(256), 0, stream>>>(splits, coords, S, cs);
    mirror_k<<<dim3(32, 32, C), dim3(256), 0, stream>>>(S);
    cand_k<<<dim3(C * NPTS), dim3(64), 0, stream>>>(S, cand8, rowsum);
    traverse_k<<<dim3(C), dim3(64), 131072, stream>>>(S, cand8, rowsum, order_f, cs);
  }
  gather_k<<<dim3(BATCH * NPTS), dim3(192), 0, stream>>>(features, order_f, out);
}

// Round 9
// 1965.464 us; speedup vs baseline: 1.5383x; 1.3219x over previous
//
#include <hip/hip_runtime.h>
#include <math.h>

#define BATCH 16
#define NPTS  2048
#define DIM   768
#define NCH   24      // 768 / 32 k-chunks
#define PAD   40      // LDS row stride in bf16 (80B): b128 reads 2-way (free)

typedef unsigned long long ull;
typedef float f32x4 __attribute__((ext_vector_type(4)));
typedef short bf8 __attribute__((ext_vector_type(8)));          // 8 bf16 = 4 VGPR

// RNE fp32 -> bf16, returned as bits with low 16 zeroed (== bf2f(f2bf(x)) bit pattern)
__device__ __forceinline__ unsigned bfr(float x) {
  unsigned u = __float_as_uint(x);
  return (u + 0x7FFFu + ((u >> 16) & 1u)) & 0xFFFF0000u;
}
__device__ __forceinline__ unsigned short f2bf(float x) {
  unsigned u = __float_as_uint(x);
  u += 0x7FFFu + ((u >> 16) & 1u);
  return (unsigned short)(u >> 16);
}

// ---------------- normalize: fn = f / max(||f||,1e-12), fp64 norm (fp32 output) ----------------
__global__ void normalize_k(const float* __restrict__ feat, float* __restrict__ fn, int cs) {
  const int rn = blockIdx.x;                 // ci*NPTS + n
  const int ci = rn >> 11, n = rn & (NPTS - 1);
  const float* src = feat + ((size_t)(cs + ci) * NPTS + n) * DIM;
  const int t = threadIdx.x;                 // 256 threads
  float f0 = src[t], f1 = src[t + 256], f2 = src[t + 512];
  double s = (double)f0 * (double)f0 + (double)f1 * (double)f1 + (double)f2 * (double)f2;
  for (int off = 32; off > 0; off >>= 1) s += __shfl_down(s, off);
  __shared__ double ps[4];
  __shared__ double rbc;
  const int lane = t & 63, wid = t >> 6;
  if (lane == 0) ps[wid] = s;
  __syncthreads();
  if (t == 0) {
    double tot = ps[0] + ps[1] + ps[2] + ps[3];
    rbc = fmax(sqrt(tot), 1e-12);
  }
  __syncthreads();
  const double r = rbc;
  float* dst = fn + ((size_t)ci * NPTS + n) * DIM;
  dst[t]       = (float)((double)f0 / r);
  dst[t + 256] = (float)((double)f1 / r);
  dst[t + 512] = (float)((double)f2 / r);
}

// ---------------- similarity: S = fn.fn^T via split-3 bf16 MFMA + 0.5*exp(-d2/1e4) ------------
// Upper-triangle 128x128 tiles (bx<=by); mirror_k fills the rest.
// Split-3 is done IN-KERNEL at staging (same RNE bit formula as the verified round-8
// pipeline -> identical b1/b2/b3 -> S bit-identical), so the workspace holds fp32 fn
// (6.3 MB/batch) instead of bf16 splits (9.4 MB/batch) and the launcher fits C=16.
// Per 16x16 output tile per k32: 6 bf16 MFMAs into 3 fp32 accumulators.
__global__ __launch_bounds__(256, 1) void gemm_k(const float* __restrict__ fn,
                                                 const float* __restrict__ coords,
                                                 float* __restrict__ S, int cs) {
  if (blockIdx.x > blockIdx.y) return;       // symmetry: skip strictly-lower tiles
  const int ci = blockIdx.z;
  const int i0 = blockIdx.x * 128;
  const int j0 = blockIdx.y * 128;
  const int tid  = threadIdx.x;              // 256
  const int lane = tid & 63, w = tid >> 6;
  const int wr = (w >> 1) * 64, wc = (w & 1) * 64;   // wave quadrant
  const int lo = lane & 15, quad = lane >> 4;

  __shared__ unsigned short At[3][128][PAD]; // 30720 B
  __shared__ unsigned short Bt[3][128][PAD]; // 30720 B

  f32x4 aH[4][4], aM[4][4], aL[4][4];
#pragma unroll
  for (int tr = 0; tr < 4; ++tr)
#pragma unroll
    for (int tc = 0; tc < 4; ++tc) {
      aH[tr][tc] = (f32x4){0.f, 0.f, 0.f, 0.f};
      aM[tr][tc] = (f32x4){0.f, 0.f, 0.f, 0.f};
      aL[tr][tc] = (f32x4){0.f, 0.f, 0.f, 0.f};
    }

  const float* fb = fn + (size_t)ci * NPTS * DIM;
  const int row  = tid >> 1;       // staging row 0..127
  const int half = tid & 1;        // 16-float sub-band of the k32 chunk
  const float* ag = fb + (size_t)(i0 + row) * DIM + half * 16;
  const float* bg = fb + (size_t)(j0 + row) * DIM + half * 16;

  float4 fa[4], fbv[4];
  // prefetch chunk 0
#pragma unroll
  for (int g = 0; g < 4; ++g) {
    fa[g]  = *(const float4*)(ag + g * 4);
    fbv[g] = *(const float4*)(bg + g * 4);
  }

#pragma unroll 1
  for (int c = 0; c < NCH; ++c) {
    __syncthreads();               // previous chunk's readers done
    {
      float wa[16], wb[16];
#pragma unroll
      for (int g = 0; g < 4; ++g) {
        wa[4 * g + 0] = fa[g].x;  wa[4 * g + 1] = fa[g].y;
        wa[4 * g + 2] = fa[g].z;  wa[4 * g + 3] = fa[g].w;
        wb[4 * g + 0] = fbv[g].x; wb[4 * g + 1] = fbv[g].y;
        wb[4 * g + 2] = fbv[g].z; wb[4 * g + 3] = fbv[g].w;
      }
      unsigned pa1[4], pa2[4], pa3[4], pb1[4], pb2[4], pb3[4];
#pragma unroll
      for (int j = 0; j < 8; j += 2) {       // words j/2 and j/2+... per pair of elems
        // A matrix, elems 2j'..: process pairs across all 16 via two sub-loops
      }
#pragma unroll
      for (int j = 0; j < 16; j += 2) {
        float w0 = wa[j], w1 = wa[j + 1];
        unsigned a0 = bfr(w0); float r0 = w0 - __uint_as_float(a0);
        unsigned a1 = bfr(w1); float r1 = w1 - __uint_as_float(a1);
        unsigned b0 = bfr(r0); float q0 = r0 - __uint_as_float(b0);
        unsigned b1 = bfr(r1); float q1 = r1 - __uint_as_float(b1);
        unsigned c0 = bfr(q0), c1 = bfr(q1);
        const int wd = j >> 1;
        if (wd < 4) { pa1[wd] = (a0 >> 16) | (a1 & 0xFFFF0000u);
                      pa2[wd] = (b0 >> 16) | (b1 & 0xFFFF0000u);
                      pa3[wd] = (c0 >> 16) | (c1 & 0xFFFF0000u); }
        else        { pa1[wd - 4] = pa1[wd - 4]; }   // unreachable; loop split below
      }
      // NOTE: the loop above covers j<16 with wd 0..7 but arrays are 4 words (8 u16)
      // per b128 slot; handled by storing in two halves below.
      // -- rebuild properly: convert first 8 elems -> slot 0 words, last 8 -> slot 1 --
      unsigned sa[2][3][4], sb[2][3][4];
#pragma unroll
      for (int h = 0; h < 2; ++h)
#pragma unroll
        for (int j = 0; j < 8; j += 2) {
          {
            float w0 = wa[8 * h + j], w1 = wa[8 * h + j + 1];
            unsigned a0 = bfr(w0); float r0 = w0 - __uint_as_float(a0);
            unsigned a1 = bfr(w1); float r1 = w1 - __uint_as_float(a1);
            unsigned b0 = bfr(r0); float q0 = r0 - __uint_as_float(b0);
            unsigned b1 = bfr(r1); float q1 = r1 - __uint_as_float(b1);
            unsigned c0 = bfr(q0), c1 = bfr(q1);
            sa[h][0][j >> 1] = (a0 >> 16) | (a1 & 0xFFFF0000u);
            sa[h][1][j >> 1] = (b0 >> 16) | (b1 & 0xFFFF0000u);
            sa[h][2][j >> 1] = (c0 >> 16) | (c1 & 0xFFFF0000u);
          }
          {
            float w0 = wb[8 * h + j], w1 = wb[8 * h + j + 1];
            unsigned a0 = bfr(w0); float r0 = w0 - __uint_as_float(a0);
            unsigned a1 = bfr(w1); float r1 = w1 - __uint_as_float(a1);
            unsigned b0 = bfr(r0); float q0 = r0 - __uint_as_float(b0);
            unsigned b1 = bfr(r1); float q1 = r1 - __uint_as_float(b1);
            unsigned c0 = bfr(q0), c1 = bfr(q1);
            sb[h][0][j >> 1] = (a0 >> 16) | (a1 & 0xFFFF0000u);
            sb[h][1][j >> 1] = (b0 >> 16) | (b1 & 0xFFFF0000u);
            sb[h][2][j >> 1] = (c0 >> 16) | (c1 & 0xFFFF0000u);
          }
        }
#pragma unroll
      for (int p = 0; p < 3; ++p) {
#pragma unroll
        for (int h = 0; h < 2; ++h) {
          *(uint4*)&At[p][row][half * 16 + 8 * h] = *(uint4*)&sa[h][p][0];
          *(uint4*)&Bt[p][row][half * 16 + 8 * h] = *(uint4*)&sb[h][p][0];
        }
      }
    }
    __syncthreads();
    if (c + 1 < NCH) {             // prefetch next chunk; overlaps MFMA below
      const int kc = (c + 1) * 32;
#pragma unroll
      for (int g = 0; g < 4; ++g) {
        fa[g]  = *(const float4*)(ag + kc + g * 4);
        fbv[g] = *(const float4*)(bg + kc + g * 4);
      }
    }
    bf8 A0[4], A1[4], A2[4], B0[4], B1[4], B2[4];
#pragma unroll
    for (int t = 0; t < 4; ++t) {
      const int rA = wr + t * 16 + lo, rB = wc + t * 16 + lo, k8 = quad * 8;
      A0[t] = *(const bf8*)&At[0][rA][k8];
      A1[t] = *(const bf8*)&At[1][rA][k8];
      A2[t] = *(const bf8*)&At[2][rA][k8];
      B0[t] = *(const bf8*)&Bt[0][rB][k8];
      B1[t] = *(const bf8*)&Bt[1][rB][k8];
      B2[t] = *(const bf8*)&Bt[2][rB][k8];
    }
#pragma unroll
    for (int tr = 0; tr < 4; ++tr)
#pragma unroll
      for (int tc = 0; tc < 4; ++tc) {
        aH[tr][tc] = __builtin_amdgcn_mfma_f32_16x16x32_bf16(A0[tr], B0[tc], aH[tr][tc], 0, 0, 0);
        aM[tr][tc] = __builtin_amdgcn_mfma_f32_16x16x32_bf16(A0[tr], B1[tc], aM[tr][tc], 0, 0, 0);
        aM[tr][tc] = __builtin_amdgcn_mfma_f32_16x16x32_bf16(A1[tr], B0[tc], aM[tr][tc], 0, 0, 0);
        aL[tr][tc] = __builtin_amdgcn_mfma_f32_16x16x32_bf16(A0[tr], B2[tc], aL[tr][tc], 0, 0, 0);
        aL[tr][tc] = __builtin_amdgcn_mfma_f32_16x16x32_bf16(A1[tr], B1[tc], aL[tr][tc], 0, 0, 0);
        aL[tr][tc] = __builtin_amdgcn_mfma_f32_16x16x32_bf16(A2[tr], B0[tc], aL[tr][tc], 0, 0, 0);
      }
  }

  // ---- probe the true C/D slot->(row,col) mapping (exact small ints in bf16/fp32) ----
  {
    const unsigned short encv = f2bf((float)lo);
    const unsigned short onev = f2bf(1.0f);
    bf8 enc, one;
#pragma unroll
    for (int t = 0; t < 8; ++t) { enc[t] = (short)encv; one[t] = (short)onev; }
    f32x4 z = (f32x4){0.f, 0.f, 0.f, 0.f};
    f32x4 d1 = __builtin_amdgcn_mfma_f32_16x16x32_bf16(enc, one, z, 0, 0, 0); // = 32*row
    f32x4 d2 = __builtin_amdgcn_mfma_f32_16x16x32_bf16(one, enc, z, 0, 0, 0); // = 32*col
    int rowp[4], colp[4];
#pragma unroll
    for (int r = 0; r < 4; ++r) {
      rowp[r] = ((int)(d1[r] * (1.0f / 32.0f))) & 15;
      colp[r] = ((int)(d2[r] * (1.0f / 32.0f))) & 15;
    }

    // epilogue: S = hi+mid+lo (fp64 sum) + 0.5*exp(-d2/1e4) (4th-order Taylor, exact regime)
    const float* cb = coords + (size_t)(cs + ci) * NPTS * 2;
    float* Sb = S + (size_t)ci * NPTS * NPTS;
#pragma unroll
    for (int r = 0; r < 4; ++r) {
      const int rl = rowp[r], cl = colp[r];
#pragma unroll
      for (int tr = 0; tr < 4; ++tr) {
        const int rowi = i0 + wr + tr * 16 + rl;
        float2 pi = *(const float2*)(cb + 2 * rowi);
        const double cix = pi.x, ciy = pi.y;
#pragma unroll
        for (int tc = 0; tc < 4; ++tc) {
          const int colj = j0 + wc + tc * 16 + cl;
          float2 pj = *(const float2*)(cb + 2 * colj);
          double dx = cix - (double)pj.x, dy = ciy - (double)pj.y;
          double x = (dx * dx + dy * dy) * (1.0 / 10000.0);
          double e = 1.0 - x * (1.0 - x * (0.5 - x * ((1.0 / 6.0) - x * (1.0 / 24.0))));
          double sem = (double)aH[tr][tc][r] + (double)aM[tr][tc][r] + (double)aL[tr][tc][r];
          Sb[(size_t)rowi * NPTS + colj] = (float)(sem + 0.5 * e);
        }
      }
    }
  }
}

// ---------------- mirror: fill strictly-lower 128-blocks from upper triangle ----------------
__global__ __launch_bounds__(256) void mirror_k(float* __restrict__ S) {
  const int Cb = blockIdx.x, Rb = blockIdx.y;
  if ((Rb >> 1) <= (Cb >> 1)) return;
  float* Sb = S + (size_t)blockIdx.z * NPTS * NPTS;
  __shared__ float t[64][65];
  const int lane = threadIdx.x & 63, w = threadIdx.x >> 6;
#pragma unroll
  for (int p = 0; p < 16; ++p) {
    const int r = w + 4 * p;
    t[r][lane] = Sb[(size_t)(Cb * 64 + r) * NPTS + Rb * 64 + lane];
  }
  __syncthreads();
#pragma unroll
  for (int p = 0; p < 16; ++p) {
    const int r = w + 4 * p;
    Sb[(size_t)(Rb * 64 + r) * NPTS + Cb * 64 + lane] = t[lane][r];
  }
}

// ---------------- monotone fp32 key ----------------
__device__ __forceinline__ unsigned mono(float f) {
  unsigned u = __float_as_uint(f);
  return (u & 0x80000000u) ? ~u : (u | 0x80000000u);
}

// ---------------- packed u64 DPP max step ----------------
#define DPP64_STEP(X, CTRL, RMASK) do {                                                   \
  unsigned lo_ = (unsigned)(X), hi_ = (unsigned)((X) >> 32);                              \
  unsigned lo2_ = (unsigned)__builtin_amdgcn_update_dpp((int)lo_, (int)lo_, CTRL, RMASK, 0xf, false); \
  unsigned hi2_ = (unsigned)__builtin_amdgcn_update_dpp((int)hi_, (int)hi_, CTRL, RMASK, 0xf, false); \
  ull o_ = ((ull)hi2_ << 32) | lo2_;                                                      \
  if (o_ > (X)) (X) = o_;                                                                 \
} while (0)

// full 64-lane argmax (slow path / start node)
__device__ __forceinline__ ull wave_amax64(ull x) {
  DPP64_STEP(x, 0x111, 0xf);
  DPP64_STEP(x, 0x112, 0xf);
  DPP64_STEP(x, 0x114, 0xf);
  DPP64_STEP(x, 0x118, 0xf);
  DPP64_STEP(x, 0x142, 0xa);
  DPP64_STEP(x, 0x143, 0xc);
  unsigned lo = (unsigned)__builtin_amdgcn_readlane((int)(unsigned)x, 63);
  unsigned hi = (unsigned)__builtin_amdgcn_readlane((int)(unsigned)(x >> 32), 63);
  return ((ull)hi << 32) | lo;
}

// ---------------- cand_k: exact top-7 + tau(=8th max) per row + fp64 rowsum ----------------
__global__ __launch_bounds__(64) void cand_k(const float* __restrict__ S,
                                             ull* __restrict__ cand8,
                                             double* __restrict__ rs) {
  const size_t r = blockIdx.x;               // ci*NPTS + row
  const int row = (int)(r & (NPTS - 1));
  const float* rowp = S + r * NPTS;
  const int lane = threadIdx.x;

  float4 q[8];
  double sum = 0.0;
#pragma unroll
  for (int c = 0; c < 8; ++c) {
    q[c] = ((const float4*)rowp)[c * 64 + lane];
    sum += (double)q[c].x; sum += (double)q[c].y; sum += (double)q[c].z; sum += (double)q[c].w;
  }
  {
    double s2 = sum;
    for (int off = 32; off > 0; off >>= 1) s2 += __shfl_down(s2, off);
    if (lane == 0) rs[r] = s2;
  }

  unsigned rem = 0;
  const int dd = row - 4 * lane;
  if (dd >= 0 && dd < 2048 && (dd & 0xFC) == 0) rem = 1u << (((dd >> 8) << 2) | (dd & 3));

  float bv; int bp;
  auto rescan = [&]() {
    bv = -INFINITY; bp = 0;
#pragma unroll
    for (int c = 0; c < 8; ++c) {
      const float xs0 = q[c].x, xs1 = q[c].y, xs2 = q[c].z, xs3 = q[c].w;
      float x0 = ((rem >> (4 * c + 0)) & 1u) ? -INFINITY : xs0;
      float x1 = ((rem >> (4 * c + 1)) & 1u) ? -INFINITY : xs1;
      float x2 = ((rem >> (4 * c + 2)) & 1u) ? -INFINITY : xs2;
      float x3 = ((rem >> (4 * c + 3)) & 1u) ? -INFINITY : xs3;
      if (x0 > bv) { bv = x0; bp = 4 * c + 0; }
      if (x1 > bv) { bv = x1; bp = 4 * c + 1; }
      if (x2 > bv) { bv = x2; bp = 4 * c + 2; }
      if (x3 > bv) { bv = x3; bp = 4 * c + 3; }
    }
  };
  rescan();

#pragma unroll 1
  for (int rnd = 0; rnd < 8; ++rnd) {
    const int gi = ((bp >> 2) << 8) + 4 * lane + (bp & 3);
    const ull pk = ((ull)mono(bv) << 32) | (unsigned)(2047 - gi);
    const ull red = wave_amax64(pk);
    if (rnd < 7) {
      if (lane == 0) cand8[r * 8 + rnd] = red;
      if (pk == red) { rem |= 1u << bp; rescan(); }
    } else {
      if (lane == 0) cand8[r * 8 + 7] = (red >> 32) << 32;
    }
  }
}

// ---------------- greedy traversal: LDS candidate table, NO speculative prefetch ----------------
// Fast path (~98% of steps): ds_read_b64 + bpermute visited-check + 3-step 8-lane DPP64
// max + readlane. Slow path loads the S row on demand (uniform branch) and eats one
// HBM round trip (~2% of steps). The round-8 speculative prefetch created a WAW stall
// (~450 cy/step) on its own 2-deep register buffer -- removed.
__global__ __launch_bounds__(64) void traverse_k(const float* __restrict__ S,
                                                 const ull* __restrict__ cand8,
                                                 const double* __restrict__ rs,
                                                 float* __restrict__ order_f, int cs) {
  extern __shared__ ull tabL[];              // [NPTS*8]
  const int ci = blockIdx.x;
  const int gb = cs + ci;
  const int lane = threadIdx.x;

  {
    float4* ls = (float4*)tabL;
    const float4* gs = (const float4*)(cand8 + (size_t)ci * NPTS * 8);
#pragma unroll 1
    for (int i0 = 0; i0 < 8192; i0 += 512) {
      float4 t[8];
#pragma unroll
      for (int j = 0; j < 8; ++j) t[j] = gs[i0 + j * 64 + lane];
#pragma unroll
      for (int j = 0; j < 8; ++j) ls[i0 + j * 64 + lane] = t[j];
    }
  }
  __syncthreads();

  // start node: argmax of fp64 rowsum (tie -> min index)
  const double* rb = rs + (size_t)ci * NPTS;
  double dv = -1.0e300; int di = 0;
#pragma unroll
  for (int c = 0; c < 32; ++c) {
    int j = c * 64 + lane;
    double v = rb[j];
    if (v > dv) { dv = v; di = j; }
  }
  for (int off = 32; off > 0; off >>= 1) {
    double vo = __shfl_down(dv, off);
    int io = __shfl_down(di, off);
    if (vo > dv || (vo == dv && io < di)) { dv = vo; di = io; }
  }
  int cur = __shfl(di, 0);

  unsigned vis = 0, visw = 0;
  if (lane == ((cur >> 2) & 63)) vis |= 1u << (((cur >> 8) << 2) | (cur & 3));
  if (lane == (cur >> 5))        visw |= 1u << (cur & 31);
  if (lane == 0) order_f[(size_t)gb * NPTS] = (float)cur;

  const float* Sb = S + (size_t)ci * NPTS * NPTS;
  const int slot = lane & 7;

#pragma unroll 1
  for (int s = 1; s < NPTS; ++s) {
    const ull e = tabL[cur * 8 + slot];                       // broadcast ds_read_b64
    const unsigned idx = 2047u - (unsigned)(e & 0xFFFFFFFFu);
    const unsigned wv = (unsigned)__shfl((int)visw, (int)(idx >> 5));
    ull mk = ((slot == 7) || ((wv >> (idx & 31)) & 1u)) ? 0ull : e;
    // 8-lane max: candidates live in lanes 0..6 of each 8-lane group; lane 7 collects.
    DPP64_STEP(mk, 0x111, 0xf);   // row_shr:1
    DPP64_STEP(mk, 0x112, 0xf);   // row_shr:2
    DPP64_STEP(mk, 0x114, 0xf);   // row_shr:4
    const unsigned kH = (unsigned)__builtin_amdgcn_readlane((int)(unsigned)(mk >> 32), 7);
    const unsigned kL = (unsigned)__builtin_amdgcn_readlane((int)(unsigned)mk, 7);
    const unsigned tH = (unsigned)__builtin_amdgcn_readlane((int)(unsigned)(e >> 32), 7);
    int nxt;
    if (kH > tH) {
      nxt = (int)(2047u - kL);
    } else {
      // slow path: load + scan the full S row (uniform branch)
      const float4* rowp = (const float4*)(Sb + (size_t)cur * NPTS);
      float4 v[8];
#pragma unroll
      for (int c = 0; c < 8; ++c) v[c] = rowp[c * 64 + lane];
      float bvv = -INFINITY; int bi = 0;
#pragma unroll
      for (int c = 0; c < 8; ++c) {
        const int base = c * 256 + 4 * lane;
        float x0 = (vis & (1u << (4 * c + 0))) ? -INFINITY : v[c].x;
        float x1 = (vis & (1u << (4 * c + 1))) ? -INFINITY : v[c].y;
        float x2 = (vis & (1u << (4 * c + 2))) ? -INFINITY : v[c].z;
        float x3 = (vis & (1u << (4 * c + 3))) ? -INFINITY : v[c].w;
        if (x0 > bvv) { bvv = x0; bi = base + 0; }
        if (x1 > bvv) { bvv = x1; bi = base + 1; }
        if (x2 > bvv) { bvv = x2; bi = base + 2; }
        if (x3 > bvv) { bvv = x3; bi = base + 3; }
      }
      const ull pk = ((ull)mono(bvv) << 32) | (unsigned)(2047 - bi);
      const ull mm = wave_amax64(pk);
      nxt = (int)(2047u - (unsigned)(mm & 0xFFFFFFFFu));
    }
    if (lane == ((nxt >> 2) & 63)) vis |= 1u << (((nxt >> 8) << 2) | (nxt & 3));
    if (lane == (nxt >> 5))        visw |= 1u << (nxt & 31);
    if (lane == 0) order_f[(size_t)gb * NPTS + s] = (float)nxt;
    cur = nxt;
  }
}

// ---------------- gather: reordered = features[order] ----------------
__global__ void gather_k(const float* __restrict__ feat, const float* __restrict__ order_f,
                         float* __restrict__ out) {
  const int bk = blockIdx.x;
  const int b = bk >> 11, k = bk & (NPTS - 1);
  const int idx = (int)order_f[(size_t)b * NPTS + k];
  const float4* src = (const float4*)(feat + ((size_t)b * NPTS + idx) * DIM);
  float4* dst = (float4*)(out + ((size_t)b * NPTS + k) * DIM);
  dst[threadIdx.x] = src[threadIdx.x];
}

extern "C" void kernel_launch(void* const* d_in, const int* in_sizes, int n_in,
                              void* d_out, int out_size, void* d_ws, size_t ws_size,
                              hipStream_t stream) {
  const float* features = (const float*)d_in[0];
  const float* coords   = (const float*)d_in[1];
  float* out = (float*)d_out;
  float* order_f = out + (size_t)BATCH * NPTS * DIM;

  static bool attr_done = false;
  if (!attr_done) {
    (void)hipFuncSetAttribute((const void*)traverse_k,
                              hipFuncAttributeMaxDynamicSharedMemorySize, 131072);
    attr_done = true;
  }

  // ws per batch: rs (N*8) + S (N*N*4) + fn (N*D*4) + cand8 (N*8*8)  == round-4 size -> C=16
  const size_t per_b = (size_t)NPTS * 8 + (size_t)NPTS * NPTS * 4 +
                       (size_t)NPTS * DIM * 4 + (size_t)NPTS * 8 * 8;
  int C = BATCH;
  while (C > 1 && per_b * (size_t)C > ws_size) C >>= 1;

  char* wp = (char*)d_ws;
  double* rowsum = (double*)wp;               wp += (size_t)C * NPTS * 8;
  float*  S      = (float*)wp;                wp += (size_t)C * NPTS * NPTS * 4;
  float*  fn     = (float*)wp;                wp += (size_t)C * NPTS * DIM * 4;
  ull*    cand8  = (ull*)wp;

  for (int cs = 0; cs < BATCH; cs += C) {
    normalize_k<<<dim3(C * NPTS), dim3(256), 0, stream>>>(features, fn, cs);
    gemm_k<<<dim3(16, 16, C), dim3(256), 0, stream>>>(fn, coords, S, cs);
    mirror_k<<<dim3(32, 32, C), dim3(256), 0, stream>>>(S);
    cand_k<<<dim3(C * NPTS), dim3(64), 0, stream>>>(S, cand8, rowsum);
    traverse_k<<<dim3(C), dim3(64), 131072, stream>>>(S, cand8, rowsum, order_f, cs);
  }
  gather_k<<<dim3(BATCH * NPTS), dim3(192), 0, stream>>>(features, order_f, out);
}

// Round 10
// 1960.437 us; speedup vs baseline: 1.5423x; 1.0026x over previous
//
#include <hip/hip_runtime.h>
#include <math.h>

#define BATCH 16
#define NPTS  2048
#define DIM   768
#define NCH   24      // 768 / 32 k-chunks

typedef unsigned long long ull;
typedef float f32x4 __attribute__((ext_vector_type(4)));
typedef short bf8 __attribute__((ext_vector_type(8)));          // 8 bf16 = 4 VGPR

// RNE fp32 -> bf16, returned as bits with low 16 zeroed (== bf2f(f2bf(x)) bit pattern)
__device__ __forceinline__ unsigned bfr(float x) {
  unsigned u = __float_as_uint(x);
  return (u + 0x7FFFu + ((u >> 16) & 1u)) & 0xFFFF0000u;
}
__device__ __forceinline__ unsigned short f2bf(float x) {
  unsigned u = __float_as_uint(x);
  u += 0x7FFFu + ((u >> 16) & 1u);
  return (unsigned short)(u >> 16);
}

// ---------------- normalize: fn = f / max(||f||,1e-12), fp64 norm (fp32 output) ----------------
__global__ void normalize_k(const float* __restrict__ feat, float* __restrict__ fn, int cs) {
  const int rn = blockIdx.x;                 // ci*NPTS + n
  const int ci = rn >> 11, n = rn & (NPTS - 1);
  const float* src = feat + ((size_t)(cs + ci) * NPTS + n) * DIM;
  const int t = threadIdx.x;                 // 256 threads
  float f0 = src[t], f1 = src[t + 256], f2 = src[t + 512];
  double s = (double)f0 * (double)f0 + (double)f1 * (double)f1 + (double)f2 * (double)f2;
  for (int off = 32; off > 0; off >>= 1) s += __shfl_down(s, off);
  __shared__ double ps[4];
  __shared__ double rbc;
  const int lane = t & 63, wid = t >> 6;
  if (lane == 0) ps[wid] = s;
  __syncthreads();
  if (t == 0) {
    double tot = ps[0] + ps[1] + ps[2] + ps[3];
    rbc = fmax(sqrt(tot), 1e-12);
  }
  __syncthreads();
  const double r = rbc;
  float* dst = fn + ((size_t)ci * NPTS + n) * DIM;
  dst[t]       = (float)((double)f0 / r);
  dst[t + 256] = (float)((double)f1 / r);
  dst[t + 512] = (float)((double)f2 / r);
}

// ---------------- similarity: S = fn.fn^T via split-3 bf16 MFMA + 0.5*exp(-d2/1e4) ------------
// Upper-triangle 128x128 tiles (bx<=by); mirror_k fills the rest.
// In-kernel split-3 (same RNE bit formula as the verified round-8/9 pipeline -> S
// bit-identical). LDS layout: one 256B row per tile-row = 16 slots x 16B; logical slot
// s (= plane*4 + k8-band, s<12) stored at phys slot s ^ (row&7). Row stride 256B == 0
// banks, so conflicts are governed purely by the XOR: every b128 write AND read puts
// exactly 8 lanes on each 4-bank group -> conflict-free (round-9's PAD=40 linear layout
// was an 8-way conflict: 4.0e7 extra LDS cycles). Prefetch for chunk c+1 is issued at
// loop top (after the convert consumes the raw regs) so HBM latency hides under
// write+barrier+frag-read+MFMA.
__global__ __launch_bounds__(256, 1) void gemm_k(const float* __restrict__ fn,
                                                 const float* __restrict__ coords,
                                                 float* __restrict__ S, int cs) {
  if (blockIdx.x > blockIdx.y) return;       // symmetry: skip strictly-lower tiles
  const int ci = blockIdx.z;
  const int i0 = blockIdx.x * 128;
  const int j0 = blockIdx.y * 128;
  const int tid  = threadIdx.x;              // 256
  const int lane = tid & 63, w = tid >> 6;
  const int wr = (w >> 1) * 64, wc = (w & 1) * 64;   // wave quadrant
  const int lo = lane & 15, quad = lane >> 4;

  __shared__ unsigned short At[128][128];    // 32 KB, XOR-swizzled 16B slots
  __shared__ unsigned short Bt[128][128];    // 32 KB

  f32x4 aH[4][4], aM[4][4], aL[4][4];
#pragma unroll
  for (int tr = 0; tr < 4; ++tr)
#pragma unroll
    for (int tc = 0; tc < 4; ++tc) {
      aH[tr][tc] = (f32x4){0.f, 0.f, 0.f, 0.f};
      aM[tr][tc] = (f32x4){0.f, 0.f, 0.f, 0.f};
      aL[tr][tc] = (f32x4){0.f, 0.f, 0.f, 0.f};
    }

  const float* fb = fn + (size_t)ci * NPTS * DIM;
  const int row  = tid >> 1;       // staging row 0..127
  const int half = tid & 1;        // 16-float sub-band of the k32 chunk
  const float* ag = fb + (size_t)(i0 + row) * DIM + half * 16;
  const float* bg = fb + (size_t)(j0 + row) * DIM + half * 16;

  float4 fa[4], fbv[4];
  // prefetch chunk 0
#pragma unroll
  for (int g = 0; g < 4; ++g) {
    fa[g]  = *(const float4*)(ag + g * 4);
    fbv[g] = *(const float4*)(bg + g * 4);
  }

#pragma unroll 1
  for (int c = 0; c < NCH; ++c) {
    // ---- convert chunk c (raw regs -> 3-way bf16 split, packed u32 pairs) ----
    float wa[16], wb[16];
#pragma unroll
    for (int g = 0; g < 4; ++g) {
      wa[4 * g + 0] = fa[g].x;  wa[4 * g + 1] = fa[g].y;
      wa[4 * g + 2] = fa[g].z;  wa[4 * g + 3] = fa[g].w;
      wb[4 * g + 0] = fbv[g].x; wb[4 * g + 1] = fbv[g].y;
      wb[4 * g + 2] = fbv[g].z; wb[4 * g + 3] = fbv[g].w;
    }
    unsigned sa[2][3][4], sb[2][3][4];
#pragma unroll
    for (int h = 0; h < 2; ++h)
#pragma unroll
      for (int j = 0; j < 8; j += 2) {
        {
          float w0 = wa[8 * h + j], w1 = wa[8 * h + j + 1];
          unsigned a0 = bfr(w0); float r0 = w0 - __uint_as_float(a0);
          unsigned a1 = bfr(w1); float r1 = w1 - __uint_as_float(a1);
          unsigned b0 = bfr(r0); float q0 = r0 - __uint_as_float(b0);
          unsigned b1 = bfr(r1); float q1 = r1 - __uint_as_float(b1);
          unsigned c0 = bfr(q0), c1 = bfr(q1);
          sa[h][0][j >> 1] = (a0 >> 16) | (a1 & 0xFFFF0000u);
          sa[h][1][j >> 1] = (b0 >> 16) | (b1 & 0xFFFF0000u);
          sa[h][2][j >> 1] = (c0 >> 16) | (c1 & 0xFFFF0000u);
        }
        {
          float w0 = wb[8 * h + j], w1 = wb[8 * h + j + 1];
          unsigned a0 = bfr(w0); float r0 = w0 - __uint_as_float(a0);
          unsigned a1 = bfr(w1); float r1 = w1 - __uint_as_float(a1);
          unsigned b0 = bfr(r0); float q0 = r0 - __uint_as_float(b0);
          unsigned b1 = bfr(r1); float q1 = r1 - __uint_as_float(b1);
          unsigned c0 = bfr(q0), c1 = bfr(q1);
          sb[h][0][j >> 1] = (a0 >> 16) | (a1 & 0xFFFF0000u);
          sb[h][1][j >> 1] = (b0 >> 16) | (b1 & 0xFFFF0000u);
          sb[h][2][j >> 1] = (c0 >> 16) | (c1 & 0xFFFF0000u);
        }
      }
    // ---- issue prefetch for chunk c+1 (raw regs now free; latency hides below) ----
    if (c + 1 < NCH) {
      const int kc = (c + 1) * 32;
#pragma unroll
      for (int g = 0; g < 4; ++g) {
        fa[g]  = *(const float4*)(ag + kc + g * 4);
        fbv[g] = *(const float4*)(bg + kc + g * 4);
      }
    }
    __syncthreads();               // previous chunk's readers done
    // ---- swizzled LDS writes: logical slot p*4 + half*2 + h, phys = slot^(row&7) ----
#pragma unroll
    for (int p = 0; p < 3; ++p)
#pragma unroll
      for (int h = 0; h < 2; ++h) {
        const int off = ((p * 4 + half * 2 + h) ^ (row & 7)) << 3;   // u16 offset
        *(uint4*)&At[row][off] = *(uint4*)&sa[h][p][0];
        *(uint4*)&Bt[row][off] = *(uint4*)&sb[h][p][0];
      }
    __syncthreads();
    // ---- swizzled fragment reads: logical slot p*4 + quad ----
    bf8 A0[4], A1[4], A2[4], B0[4], B1[4], B2[4];
#pragma unroll
    for (int t = 0; t < 4; ++t) {
      const int rA = wr + t * 16 + lo, rB = wc + t * 16 + lo;
      const int xA = rA & 7, xB = rB & 7;
      A0[t] = *(const bf8*)&At[rA][((quad + 0) ^ xA) << 3];
      A1[t] = *(const bf8*)&At[rA][((quad + 4) ^ xA) << 3];
      A2[t] = *(const bf8*)&At[rA][((quad + 8) ^ xA) << 3];
      B0[t] = *(const bf8*)&Bt[rB][((quad + 0) ^ xB) << 3];
      B1[t] = *(const bf8*)&Bt[rB][((quad + 4) ^ xB) << 3];
      B2[t] = *(const bf8*)&Bt[rB][((quad + 8) ^ xB) << 3];
    }
#pragma unroll
    for (int tr = 0; tr < 4; ++tr)
#pragma unroll
      for (int tc = 0; tc < 4; ++tc) {
        aH[tr][tc] = __builtin_amdgcn_mfma_f32_16x16x32_bf16(A0[tr], B0[tc], aH[tr][tc], 0, 0, 0);
        aM[tr][tc] = __builtin_amdgcn_mfma_f32_16x16x32_bf16(A0[tr], B1[tc], aM[tr][tc], 0, 0, 0);
        aM[tr][tc] = __builtin_amdgcn_mfma_f32_16x16x32_bf16(A1[tr], B0[tc], aM[tr][tc], 0, 0, 0);
        aL[tr][tc] = __builtin_amdgcn_mfma_f32_16x16x32_bf16(A0[tr], B2[tc], aL[tr][tc], 0, 0, 0);
        aL[tr][tc] = __builtin_amdgcn_mfma_f32_16x16x32_bf16(A1[tr], B1[tc], aL[tr][tc], 0, 0, 0);
        aL[tr][tc] = __builtin_amdgcn_mfma_f32_16x16x32_bf16(A2[tr], B0[tc], aL[tr][tc], 0, 0, 0);
      }
  }

  // ---- probe the true C/D slot->(row,col) mapping (exact small ints in bf16/fp32) ----
  {
    const unsigned short encv = f2bf((float)lo);
    const unsigned short onev = f2bf(1.0f);
    bf8 enc, one;
#pragma unroll
    for (int t = 0; t < 8; ++t) { enc[t] = (short)encv; one[t] = (short)onev; }
    f32x4 z = (f32x4){0.f, 0.f, 0.f, 0.f};
    f32x4 d1 = __builtin_amdgcn_mfma_f32_16x16x32_bf16(enc, one, z, 0, 0, 0); // = 32*row
    f32x4 d2 = __builtin_amdgcn_mfma_f32_16x16x32_bf16(one, enc, z, 0, 0, 0); // = 32*col
    int rowp[4], colp[4];
#pragma unroll
    for (int r = 0; r < 4; ++r) {
      rowp[r] = ((int)(d1[r] * (1.0f / 32.0f))) & 15;
      colp[r] = ((int)(d2[r] * (1.0f / 32.0f))) & 15;
    }

    // epilogue: S = hi+mid+lo (fp64 sum) + 0.5*exp(-d2/1e4) (4th-order Taylor, exact regime)
    const float* cb = coords + (size_t)(cs + ci) * NPTS * 2;
    float* Sb = S + (size_t)ci * NPTS * NPTS;
#pragma unroll
    for (int r = 0; r < 4; ++r) {
      const int rl = rowp[r], cl = colp[r];
#pragma unroll
      for (int tr = 0; tr < 4; ++tr) {
        const int rowi = i0 + wr + tr * 16 + rl;
        float2 pi = *(const float2*)(cb + 2 * rowi);
        const double cix = pi.x, ciy = pi.y;
#pragma unroll
        for (int tc = 0; tc < 4; ++tc) {
          const int colj = j0 + wc + tc * 16 + cl;
          float2 pj = *(const float2*)(cb + 2 * colj);
          double dx = cix - (double)pj.x, dy = ciy - (double)pj.y;
          double x = (dx * dx + dy * dy) * (1.0 / 10000.0);
          double e = 1.0 - x * (1.0 - x * (0.5 - x * ((1.0 / 6.0) - x * (1.0 / 24.0))));
          double sem = (double)aH[tr][tc][r] + (double)aM[tr][tc][r] + (double)aL[tr][tc][r];
          Sb[(size_t)rowi * NPTS + colj] = (float)(sem + 0.5 * e);
        }
      }
    }
  }
}

// ---------------- mirror: fill strictly-lower 128-blocks from upper triangle ----------------
__global__ __launch_bounds__(256) void mirror_k(float* __restrict__ S) {
  const int Cb = blockIdx.x, Rb = blockIdx.y;
  if ((Rb >> 1) <= (Cb >> 1)) return;
  float* Sb = S + (size_t)blockIdx.z * NPTS * NPTS;
  __shared__ float t[64][65];
  const int lane = threadIdx.x & 63, w = threadIdx.x >> 6;
#pragma unroll
  for (int p = 0; p < 16; ++p) {
    const int r = w + 4 * p;
    t[r][lane] = Sb[(size_t)(Cb * 64 + r) * NPTS + Rb * 64 + lane];
  }
  __syncthreads();
#pragma unroll
  for (int p = 0; p < 16; ++p) {
    const int r = w + 4 * p;
    Sb[(size_t)(Rb * 64 + r) * NPTS + Cb * 64 + lane] = t[lane][r];
  }
}

// ---------------- monotone fp32 key ----------------
__device__ __forceinline__ unsigned mono(float f) {
  unsigned u = __float_as_uint(f);
  return (u & 0x80000000u) ? ~u : (u | 0x80000000u);
}

// ---------------- packed u64 DPP max step ----------------
#define DPP64_STEP(X, CTRL, RMASK) do {                                                   \
  unsigned lo_ = (unsigned)(X), hi_ = (unsigned)((X) >> 32);                              \
  unsigned lo2_ = (unsigned)__builtin_amdgcn_update_dpp((int)lo_, (int)lo_, CTRL, RMASK, 0xf, false); \
  unsigned hi2_ = (unsigned)__builtin_amdgcn_update_dpp((int)hi_, (int)hi_, CTRL, RMASK, 0xf, false); \
  ull o_ = ((ull)hi2_ << 32) | lo2_;                                                      \
  if (o_ > (X)) (X) = o_;                                                                 \
} while (0)

// full 64-lane argmax (slow path / start node)
__device__ __forceinline__ ull wave_amax64(ull x) {
  DPP64_STEP(x, 0x111, 0xf);
  DPP64_STEP(x, 0x112, 0xf);
  DPP64_STEP(x, 0x114, 0xf);
  DPP64_STEP(x, 0x118, 0xf);
  DPP64_STEP(x, 0x142, 0xa);
  DPP64_STEP(x, 0x143, 0xc);
  unsigned lo = (unsigned)__builtin_amdgcn_readlane((int)(unsigned)x, 63);
  unsigned hi = (unsigned)__builtin_amdgcn_readlane((int)(unsigned)(x >> 32), 63);
  return ((ull)hi << 32) | lo;
}

// ---------------- cand_k: exact top-7 + tau(=8th max) per row + fp64 rowsum ----------------
__global__ __launch_bounds__(64) void cand_k(const float* __restrict__ S,
                                             ull* __restrict__ cand8,
                                             double* __restrict__ rs) {
  const size_t r = blockIdx.x;               // ci*NPTS + row
  const int row = (int)(r & (NPTS - 1));
  const float* rowp = S + r * NPTS;
  const int lane = threadIdx.x;

  float4 q[8];
  double sum = 0.0;
#pragma unroll
  for (int c = 0; c < 8; ++c) {
    q[c] = ((const float4*)rowp)[c * 64 + lane];
    sum += (double)q[c].x; sum += (double)q[c].y; sum += (double)q[c].z; sum += (double)q[c].w;
  }
  {
    double s2 = sum;
    for (int off = 32; off > 0; off >>= 1) s2 += __shfl_down(s2, off);
    if (lane == 0) rs[r] = s2;
  }

  unsigned rem = 0;
  const int dd = row - 4 * lane;
  if (dd >= 0 && dd < 2048 && (dd & 0xFC) == 0) rem = 1u << (((dd >> 8) << 2) | (dd & 3));

  float bv; int bp;
  auto rescan = [&]() {
    bv = -INFINITY; bp = 0;
#pragma unroll
    for (int c = 0; c < 8; ++c) {
      const float xs0 = q[c].x, xs1 = q[c].y, xs2 = q[c].z, xs3 = q[c].w;
      float x0 = ((rem >> (4 * c + 0)) & 1u) ? -INFINITY : xs0;
      float x1 = ((rem >> (4 * c + 1)) & 1u) ? -INFINITY : xs1;
      float x2 = ((rem >> (4 * c + 2)) & 1u) ? -INFINITY : xs2;
      float x3 = ((rem >> (4 * c + 3)) & 1u) ? -INFINITY : xs3;
      if (x0 > bv) { bv = x0; bp = 4 * c + 0; }
      if (x1 > bv) { bv = x1; bp = 4 * c + 1; }
      if (x2 > bv) { bv = x2; bp = 4 * c + 2; }
      if (x3 > bv) { bv = x3; bp = 4 * c + 3; }
    }
  };
  rescan();

#pragma unroll 1
  for (int rnd = 0; rnd < 8; ++rnd) {
    const int gi = ((bp >> 2) << 8) + 4 * lane + (bp & 3);
    const ull pk = ((ull)mono(bv) << 32) | (unsigned)(2047 - gi);
    const ull red = wave_amax64(pk);
    if (rnd < 7) {
      if (lane == 0) cand8[r * 8 + rnd] = red;
      if (pk == red) { rem |= 1u << bp; rescan(); }
    } else {
      if (lane == 0) cand8[r * 8 + 7] = (red >> 32) << 32;
    }
  }
}

// ---------------- greedy traversal: LDS candidate table, no speculative prefetch ----------------
__global__ __launch_bounds__(64) void traverse_k(const float* __restrict__ S,
                                                 const ull* __restrict__ cand8,
                                                 const double* __restrict__ rs,
                                                 float* __restrict__ order_f, int cs) {
  extern __shared__ ull tabL[];              // [NPTS*8]
  const int ci = blockIdx.x;
  const int gb = cs + ci;
  const int lane = threadIdx.x;

  {
    float4* ls = (float4*)tabL;
    const float4* gs = (const float4*)(cand8 + (size_t)ci * NPTS * 8);
#pragma unroll 1
    for (int i0 = 0; i0 < 8192; i0 += 512) {
      float4 t[8];
#pragma unroll
      for (int j = 0; j < 8; ++j) t[j] = gs[i0 + j * 64 + lane];
#pragma unroll
      for (int j = 0; j < 8; ++j) ls[i0 + j * 64 + lane] = t[j];
    }
  }
  __syncthreads();

  // start node: argmax of fp64 rowsum (tie -> min index)
  const double* rb = rs + (size_t)ci * NPTS;
  double dv = -1.0e300; int di = 0;
#pragma unroll
  for (int c = 0; c < 32; ++c) {
    int j = c * 64 + lane;
    double v = rb[j];
    if (v > dv) { dv = v; di = j; }
  }
  for (int off = 32; off > 0; off >>= 1) {
    double vo = __shfl_down(dv, off);
    int io = __shfl_down(di, off);
    if (vo > dv || (vo == dv && io < di)) { dv = vo; di = io; }
  }
  int cur = __shfl(di, 0);

  unsigned vis = 0, visw = 0;
  if (lane == ((cur >> 2) & 63)) vis |= 1u << (((cur >> 8) << 2) | (cur & 3));
  if (lane == (cur >> 5))        visw |= 1u << (cur & 31);
  if (lane == 0) order_f[(size_t)gb * NPTS] = (float)cur;

  const float* Sb = S + (size_t)ci * NPTS * NPTS;
  const int slot = lane & 7;

#pragma unroll 1
  for (int s = 1; s < NPTS; ++s) {
    const ull e = tabL[cur * 8 + slot];                       // broadcast ds_read_b64
    const unsigned idx = 2047u - (unsigned)(e & 0xFFFFFFFFu);
    const unsigned wv = (unsigned)__shfl((int)visw, (int)(idx >> 5));
    ull mk = ((slot == 7) || ((wv >> (idx & 31)) & 1u)) ? 0ull : e;
    DPP64_STEP(mk, 0x111, 0xf);   // row_shr:1
    DPP64_STEP(mk, 0x112, 0xf);   // row_shr:2
    DPP64_STEP(mk, 0x114, 0xf);   // row_shr:4
    const unsigned kH = (unsigned)__builtin_amdgcn_readlane((int)(unsigned)(mk >> 32), 7);
    const unsigned kL = (unsigned)__builtin_amdgcn_readlane((int)(unsigned)mk, 7);
    const unsigned tH = (unsigned)__builtin_amdgcn_readlane((int)(unsigned)(e >> 32), 7);
    int nxt;
    if (kH > tH) {
      nxt = (int)(2047u - kL);
    } else {
      // slow path: load + scan the full S row (uniform branch)
      const float4* rowp = (const float4*)(Sb + (size_t)cur * NPTS);
      float4 v[8];
#pragma unroll
      for (int c = 0; c < 8; ++c) v[c] = rowp[c * 64 + lane];
      float bvv = -INFINITY; int bi = 0;
#pragma unroll
      for (int c = 0; c < 8; ++c) {
        const int base = c * 256 + 4 * lane;
        float x0 = (vis & (1u << (4 * c + 0))) ? -INFINITY : v[c].x;
        float x1 = (vis & (1u << (4 * c + 1))) ? -INFINITY : v[c].y;
        float x2 = (vis & (1u << (4 * c + 2))) ? -INFINITY : v[c].z;
        float x3 = (vis & (1u << (4 * c + 3))) ? -INFINITY : v[c].w;
        if (x0 > bvv) { bvv = x0; bi = base + 0; }
        if (x1 > bvv) { bvv = x1; bi = base + 1; }
        if (x2 > bvv) { bvv = x2; bi = base + 2; }
        if (x3 > bvv) { bvv = x3; bi = base + 3; }
      }
      const ull pk = ((ull)mono(bvv) << 32) | (unsigned)(2047 - bi);
      const ull mm = wave_amax64(pk);
      nxt = (int)(2047u - (unsigned)(mm & 0xFFFFFFFFu));
    }
    if (lane == ((nxt >> 2) & 63)) vis |= 1u << (((nxt >> 8) << 2) | (nxt & 3));
    if (lane == (nxt >> 5))        visw |= 1u << (nxt & 31);
    if (lane == 0) order_f[(size_t)gb * NPTS + s] = (float)nxt;
    cur = nxt;
  }
}

// ---------------- gather: reordered = features[order] ----------------
__global__ void gather_k(const float* __restrict__ feat, const float* __restrict__ order_f,
                         float* __restrict__ out) {
  const int bk = blockIdx.x;
  const int b = bk >> 11, k = bk & (NPTS - 1);
  const int idx = (int)order_f[(size_t)b * NPTS + k];
  const float4* src = (const float4*)(feat + ((size_t)b * NPTS + idx) * DIM);
  float4* dst = (float4*)(out + ((size_t)b * NPTS + k) * DIM);
  dst[threadIdx.x] = src[threadIdx.x];
}

extern "C" void kernel_launch(void* const* d_in, const int* in_sizes, int n_in,
                              void* d_out, int out_size, void* d_ws, size_t ws_size,
                              hipStream_t stream) {
  const float* features = (const float*)d_in[0];
  const float* coords   = (const float*)d_in[1];
  float* out = (float*)d_out;
  float* order_f = out + (size_t)BATCH * NPTS * DIM;

  static bool attr_done = false;
  if (!attr_done) {
    (void)hipFuncSetAttribute((const void*)traverse_k,
                              hipFuncAttributeMaxDynamicSharedMemorySize, 131072);
    attr_done = true;
  }

  // ws per batch: rs (N*8) + S (N*N*4) + fn (N*D*4) + cand8 (N*8*8)  -> C=16
  const size_t per_b = (size_t)NPTS * 8 + (size_t)NPTS * NPTS * 4 +
                       (size_t)NPTS * DIM * 4 + (size_t)NPTS * 8 * 8;
  int C = BATCH;
  while (C > 1 && per_b * (size_t)C > ws_size) C >>= 1;

  char* wp = (char*)d_ws;
  double* rowsum = (double*)wp;               wp += (size_t)C * NPTS * 8;
  float*  S      = (float*)wp;                wp += (size_t)C * NPTS * NPTS * 4;
  float*  fn     = (float*)wp;                wp += (size_t)C * NPTS * DIM * 4;
  ull*    cand8  = (ull*)wp;

  for (int cs = 0; cs < BATCH; cs += C) {
    normalize_k<<<dim3(C * NPTS), dim3(256), 0, stream>>>(features, fn, cs);
    gemm_k<<<dim3(16, 16, C), dim3(256), 0, stream>>>(fn, coords, S, cs);
    mirror_k<<<dim3(32, 32, C), dim3(256), 0, stream>>>(S);
    cand_k<<<dim3(C * NPTS), dim3(64), 0, stream>>>(S, cand8, rowsum);
    traverse_k<<<dim3(C), dim3(64), 131072, stream>>>(S, cand8, rowsum, order_f, cs);
  }
  gather_k<<<dim3(BATCH * NPTS), dim3(192), 0, stream>>>(features, order_f, out);
}